// Round 13
// baseline (305.192 us; speedup 1.0000x reference)
//
#include <hip/hip_runtime.h>
#include <hip/hip_bf16.h>
#include <vector>
#include <cmath>
#include <cstring>

using bf16 = __hip_bfloat16;
typedef short s16x8 __attribute__((ext_vector_type(8)));
typedef float f32x4 __attribute__((ext_vector_type(4)));

static constexpr int kH = 16, kD = 128, kNB = 1024, kML = 512, kQL = 2048, kDM = 2048;

// counted-vmcnt barrier (m201 pattern)
#define VMB(N) do { asm volatile("s_waitcnt vmcnt(" #N ")" ::: "memory"); \
                    __builtin_amdgcn_s_barrier(); \
                    asm volatile("" ::: "memory"); } while (0)
#define VMLB(N) do { asm volatile("s_waitcnt vmcnt(" #N ") lgkmcnt(0)" ::: "memory"); \
                     __builtin_amdgcn_s_barrier(); \
                     asm volatile("" ::: "memory"); } while (0)
// bank-conflict swizzle for VALU-staged (ds_write) LDS tiles; involution,
// applied identically on write and read. NOT used on global_load_lds tiles.
#define SWZ(c) ((c) ^ (((c) >> 4) & 3))

// ================= host precompute of Gt (input-independent) =================
static void compute_Gt_host(float* Gt) {
  const int n = kNB, P = 2 * kML;
  std::vector<double> F((size_t)n * P), A((size_t)n * n), pos(P);
  const double shift = 1.0 / (double)P;
  const double p0 = -0.5 + shift, p1 = 1.5 - shift;
  for (int i = 0; i < P; i++) pos[i] = p0 + (p1 - p0) * (double)i / (double)(P - 1);
  const double c0 = 0.3989422804014327;
  std::vector<int> lo(n), hi(n);
  for (int b = 0; b < n; b++) {
    double mu = (double)(b >> 1) / 511.0;
    double sg = (b & 1) ? 0.01 : 0.005;
    double c = c0 / sg;
    double* Fb = &F[(size_t)b * P];
    for (int i = 0; i < P; i++) { double t = (pos[i] - mu) / sg; Fb[i] = c * exp(-0.5 * t * t); }
    int l = 0; while (l < P - 1 && pos[l] < mu - 14.0 * sg) l++;
    int h = P - 1; while (h > 0 && pos[h] > mu + 14.0 * sg) h--;
    lo[b] = l; hi[b] = h;
  }
  for (int i = 0; i < n; i++) {
    const double* fi = &F[(size_t)i * P];
    for (int j = 0; j <= i; j++) {
      const double* fj = &F[(size_t)j * P];
      int a = lo[i] > lo[j] ? lo[i] : lo[j];
      int b2 = hi[i] < hi[j] ? hi[i] : hi[j];
      double s = 0.0;
      for (int k2 = a; k2 <= b2; k2++) s += fi[k2] * fj[k2];
      A[(size_t)i * n + j] = s;
      if (i != j) A[(size_t)j * n + i] = s;
    }
    A[(size_t)i * n + i] += 0.5;
  }
  for (int j = 0; j < n; j++) {  // Cholesky
    double* Aj = &A[(size_t)j * n];
    double d = Aj[j];
    for (int k2 = 0; k2 < j; k2++) d -= Aj[k2] * Aj[k2];
    d = std::sqrt(d); Aj[j] = d;
    double inv = 1.0 / d;
    for (int i = j + 1; i < n; i++) {
      double* Ai = &A[(size_t)i * n];
      double s = Ai[j];
      for (int k2 = 0; k2 < j; k2++) s -= Ai[k2] * Aj[k2];
      Ai[j] = s * inv;
    }
  }
  for (int i = 0; i < n; i++) {  // L Y = F
    double* yi = &F[(size_t)i * P];
    const double* Ai = &A[(size_t)i * n];
    for (int k2 = 0; k2 < i; k2++) {
      double lik = Ai[k2];
      const double* yk = &F[(size_t)k2 * P];
      for (int t = 0; t < P; t++) yi[t] -= lik * yk[t];
    }
    double inv = 1.0 / Ai[i];
    for (int t = 0; t < P; t++) yi[t] *= inv;
  }
  for (int i = n - 1; i >= 0; i--) {  // L^T X = Y
    double* xi = &F[(size_t)i * P];
    for (int k2 = i + 1; k2 < n; k2++) {
      double lki = A[(size_t)k2 * n + i];
      const double* xk = &F[(size_t)k2 * P];
      for (int t = 0; t < P; t++) xi[t] -= lki * xk[t];
    }
    double inv = 1.0 / A[(size_t)i * n + i];
    for (int t = 0; t < P; t++) xi[t] *= inv;
  }
  for (int b = 0; b < n; b++)
    for (int l = 0; l < kML; l++)
      Gt[(size_t)b * kML + l] = (float)F[(size_t)b * P + (kML / 2) + l];
}

static unsigned short f2bf_host(float x) {
  unsigned u; std::memcpy(&u, &x, 4);
  unsigned r = (u + 0x7FFFu + ((u >> 16) & 1u)) >> 16;
  return (unsigned short)r;
}
static float bf2f_host(unsigned short b) {
  unsigned u = ((unsigned)b) << 16; float f; std::memcpy(&f, &u, 4); return f;
}

namespace {
struct Init {
  float* d_GtTf = nullptr;           // f32 GtT[l][n]  [512][1024]
  unsigned short* d_Gth = nullptr;   // bf16-hi Gt[n][l]  [1024][512]
  unsigned short* d_Gtl = nullptr;   // bf16-lo Gt[n][l]  [1024][512]
  float* h_GtTf_pinned = nullptr;
  unsigned short* h_Gth_pinned = nullptr;
  unsigned short* h_Gtl_pinned = nullptr;
  std::vector<float> h_GtTf;
  std::vector<unsigned short> h_Gth, h_Gtl;
  Init() {
    std::vector<float> h_Gt((size_t)kNB * kML);
    compute_Gt_host(h_Gt.data());
    h_GtTf.resize(h_Gt.size());
    h_Gth.resize(h_Gt.size());
    h_Gtl.resize(h_Gt.size());
    for (int n = 0; n < kNB; n++)
      for (int l = 0; l < kML; l++) {
        float v = h_Gt[(size_t)n * kML + l];
        h_GtTf[(size_t)l * kNB + n] = v;
        unsigned short hb = f2bf_host(v);
        h_Gth[(size_t)n * kML + l] = hb;
        h_Gtl[(size_t)n * kML + l] = f2bf_host(v - bf2f_host(hb));
      }
    const size_t fb = h_Gt.size() * 4, bb = h_Gt.size() * 2;
    if (hipMalloc((void**)&d_GtTf, fb) == hipSuccess) {
      if (hipMemcpy(d_GtTf, h_GtTf.data(), fb, hipMemcpyHostToDevice) != hipSuccess) { hipFree(d_GtTf); d_GtTf = nullptr; }
    }
    if (hipMalloc((void**)&d_Gth, bb) == hipSuccess) {
      if (hipMemcpy(d_Gth, h_Gth.data(), bb, hipMemcpyHostToDevice) != hipSuccess) { hipFree(d_Gth); d_Gth = nullptr; }
    }
    if (hipMalloc((void**)&d_Gtl, bb) == hipSuccess) {
      if (hipMemcpy(d_Gtl, h_Gtl.data(), bb, hipMemcpyHostToDevice) != hipSuccess) { hipFree(d_Gtl); d_Gtl = nullptr; }
    }
    if (!d_GtTf && hipHostMalloc((void**)&h_GtTf_pinned, fb, 0) == hipSuccess)
      std::memcpy(h_GtTf_pinned, h_GtTf.data(), fb);
    if (!d_Gth && hipHostMalloc((void**)&h_Gth_pinned, bb, 0) == hipSuccess)
      std::memcpy(h_Gth_pinned, h_Gth.data(), bb);
    if (!d_Gtl && hipHostMalloc((void**)&h_Gtl_pinned, bb, 0) == hipSuccess)
      std::memcpy(h_Gtl_pinned, h_Gtl.data(), bb);
  }
};
Init g_init;
}

// ================= device helpers =================
__device__ inline short f2bf(float x) {
  unsigned u = __float_as_uint(x);
  unsigned r = (u + 0x7FFFu + ((u >> 16) & 1u)) >> 16;
  return (short)r;
}
__device__ inline float bf2f(short b) {
  return __uint_as_float(((unsigned)(unsigned short)b) << 16);
}

// async global->LDS, 16 B per lane; LDS dest is wave-uniform base + lane*16.
__device__ inline void gload16(const void* g, void* l) {
  __builtin_amdgcn_global_load_lds(
      (__attribute__((address_space(1))) void*)(g),
      (__attribute__((address_space(3))) void*)(l),
      16, 0, 0);
}

// local dtype detection: read first 512 ushorts of q; exponent-field >= 0x98
// occurs (w.h.p.) iff data is f32 (mantissa low-halves are ~uniform).
__device__ inline int detect_local(const unsigned short* q) {
  int bad = 0;
  for (int i = threadIdx.x; i < 512; i += 256) {
    int e = (q[i] >> 7) & 0xFF;
    if (e >= 0x98) bad = 1;
  }
  __shared__ int s[256];
  s[threadIdx.x] = bad; __syncthreads();
  for (int k2 = 128; k2 > 0; k2 >>= 1) {
    if (threadIdx.x < k2) s[threadIdx.x] |= s[threadIdx.x + k2];
    __syncthreads();
  }
  return s[0];
}

// ===== fused prep: dtype detect + convert k and Wv to bf16; publish flag ======
// grid: [0,1024) -> k (512x2048), [1024,5120) -> Wv (2048x2048). 4 elems/thread.
__global__ __launch_bounds__(256) void prep_kernel(const unsigned short* __restrict__ q,
                                                   const void* __restrict__ kin,
                                                   const void* __restrict__ Wv,
                                                   short* __restrict__ k_bf,
                                                   short* __restrict__ Wv_bf,
                                                   int* __restrict__ flag) {
  const int f32 = detect_local(q);
  if (blockIdx.x == 0 && threadIdx.x == 0) *flag = f32;
  const void* src; short* dst; int i;
  if (blockIdx.x < 1024) { src = kin; dst = k_bf; i = blockIdx.x * 256 + threadIdx.x; }
  else { src = Wv; dst = Wv_bf; i = (blockIdx.x - 1024) * 256 + threadIdx.x; }
  if (f32) {
    float4 v = ((const float4*)src)[i];
    short4 o; o.x = f2bf(v.x); o.y = f2bf(v.y); o.z = f2bf(v.z); o.w = f2bf(v.w);
    ((short4*)dst)[i] = o;
  } else {
    ((short4*)dst)[i] = ((const short4*)src)[i];
  }
}

// elementwise convert (f32|bf16 in) -> bf16, 4 elems/thread (used for Wo)
__global__ __launch_bounds__(256) void conv_bf16(const void* __restrict__ in,
                                                 short* __restrict__ out, int n4,
                                                 const int* __restrict__ flag) {
  int i = blockIdx.x * 256 + threadIdx.x;
  if (i >= n4) return;
  if (*flag) {
    float4 v = ((const float4*)in)[i];
    short4 o; o.x = f2bf(v.x); o.y = f2bf(v.y); o.z = f2bf(v.z); o.w = f2bf(v.w);
    ((short4*)out)[i] = o;
  } else {
    ((short4*)out)[i] = ((const short4*)in)[i];
  }
}

// ===== exact f32 mu/sigma path =====
__global__ __launch_bounds__(256) void gw_kernel(const float* __restrict__ GtT,
                                                 const void* __restrict__ wmu,
                                                 const void* __restrict__ wsg,
                                                 float* __restrict__ gw,
                                                 const int* __restrict__ flag) {
  const bool f32 = (*flag != 0);
  const int l = blockIdx.x, t = threadIdx.x;
  const float* row = GtT + (long long)l * kNB;
  float a = 0.f, b = 0.f;
  for (int n = t; n < kNB; n += 256) {
    float g = row[n];
    float wm_ = f32 ? ((const float*)wmu)[n] : bf2f(((const short*)wmu)[n]);
    float ws_ = f32 ? ((const float*)wsg)[n] : bf2f(((const short*)wsg)[n]);
    a += g * wm_; b += g * ws_;
  }
  __shared__ float red[2][256];
  red[0][t] = a; red[1][t] = b;
  __syncthreads();
  for (int s = 128; s > 0; s >>= 1) {
    if (t < s) { red[0][t] += red[0][t + s]; red[1][t] += red[1][t + s]; }
    __syncthreads();
  }
  if (t == 0) { gw[l] = red[0][0]; gw[kML + l] = red[1][0]; }
}

// bw[j] = sum_l k[l][j] * gw[l]  -- atomic-free: grid 8 x 256, one j per thread.
__global__ __launch_bounds__(256) void bwk_kernel(const void* __restrict__ kin,
                                                  const float* __restrict__ gw,
                                                  float* __restrict__ bw,
                                                  const int* __restrict__ flag) {
  const bool f32 = (*flag != 0);
  int j = blockIdx.x * 256 + threadIdx.x;
  float a = 0.f, b = 0.f;
#pragma unroll 4
  for (int l = 0; l < kML; l++) {
    float kv = f32 ? ((const float*)kin)[(long long)l * kDM + j]
                   : bf2f(((const short*)kin)[(long long)l * kDM + j]);
    a += kv * gw[l]; b += kv * gw[kML + l];
  }
  bw[j] = a;
  bw[kDM + j] = b;
}

__global__ __launch_bounds__(256) void kw_kernel(const void* __restrict__ Wk,
                                                 const float* __restrict__ bw,
                                                 float* __restrict__ kw,
                                                 const int* __restrict__ flag) {
  const bool f32 = (*flag != 0);
  int i = blockIdx.x;
  float smu = 0.f, ssg = 0.f;
  if (f32) {
    const float* row = (const float*)Wk + (long long)i * kDM;
    for (int j = threadIdx.x; j < kDM; j += 256) { float w = row[j]; smu += w * bw[j]; ssg += w * bw[kDM + j]; }
  } else {
    const short* row = (const short*)Wk + (long long)i * kDM;
    for (int j = threadIdx.x; j < kDM; j += 256) { float w = bf2f(row[j]); smu += w * bw[j]; ssg += w * bw[kDM + j]; }
  }
  __shared__ float red[2][256];
  red[0][threadIdx.x] = smu; red[1][threadIdx.x] = ssg;
  __syncthreads();
  for (int s = 128; s > 0; s >>= 1) {
    if (threadIdx.x < (unsigned)s) {
      red[0][threadIdx.x] += red[0][threadIdx.x + s];
      red[1][threadIdx.x] += red[1][threadIdx.x + s];
    }
    __syncthreads();
  }
  if (threadIdx.x == 0) { kw[i] = red[0][0]; kw[kDM + i] = red[1][0]; }
}

// ===== MFMA GEMM: C[M,N] = A[M,K] @ BT[N,K]^T (bf16 in, f32 acc) ===============
// Tile 128x64, BK=64. 3-buffer pipeline, prefetch distance 2, counted vmcnt(6).
// LDS 72 KB -> 2 blocks/CU (grid 512). CSTORE: 0 = bf16; 2 = runtime dtype.
template <int CSTORE>
__global__ __launch_bounds__(256) void mfma_gemm_bt(
    const short* __restrict__ A0, int lda, long long sA,
    const short* __restrict__ BT0, int ldb, long long sB,
    void* __restrict__ C0, int ldc, long long sC,
    int K, const int* __restrict__ flag) {
  __shared__ s16x8 lA[3][1024];  // [buf][ks*512 + sub*64 + lane]
  __shared__ s16x8 lB[3][512];   // [buf][ks*256 + sub*64 + lane]
  const short* A = A0 + (long long)blockIdx.z * sA;
  const short* BT = BT0 + (long long)blockIdx.z * sB;
  const int t = threadIdx.x;
  const int wave = t >> 6, lane = t & 63;
  const int quad = lane >> 4, l16 = lane & 15;
  const int wm = wave >> 1, wn = wave & 1;
  const int m0 = blockIdx.y * 128, n0 = blockIdx.x * 64;
  const int srow = lane & 15, skc = lane >> 4;
  auto stage = [&](int b, int kk) {              // 6 gload16 per lane
#pragma unroll
    for (int i = 0; i < 2; i++) {
      int sub = wave + i * 4;         // A subtiles 0..7
      int m = sub * 16 + srow;
#pragma unroll
      for (int ks = 0; ks < 2; ks++)
        gload16(A + (long long)(m0 + m) * lda + kk + ks * 32 + skc * 8,
                &lA[b][ks * 512 + sub * 64]);
    }
    int mB = wave * 16 + srow;        // B subtiles 0..3, one per wave
#pragma unroll
    for (int ks = 0; ks < 2; ks++)
      gload16(BT + (long long)(n0 + mB) * ldb + kk + ks * 32 + skc * 8,
              &lB[b][ks * 256 + wave * 64]);
  };
  f32x4 acc[4][2];
  const f32x4 z = {0.f, 0.f, 0.f, 0.f};
#pragma unroll
  for (int i = 0; i < 4; i++)
#pragma unroll
    for (int j = 0; j < 2; j++) acc[i][j] = z;
  stage(0, 0);
  stage(1, 64);
  VMB(6);                       // tile 0 landed; tile 1 in flight
  const int NT = K >> 6;
  int cur = 0, pf = 2;
  for (int tt = 0; tt < NT; ++tt) {
    const bool more = (tt + 2 < NT);
    if (more) stage(pf, (tt + 2) << 6);
#pragma unroll
    for (int ks = 0; ks < 2; ks++) {
      s16x8 af[4], bfr[2];
#pragma unroll
      for (int i = 0; i < 4; i++) af[i] = lA[cur][ks * 512 + (wm * 4 + i) * 64 + lane];
#pragma unroll
      for (int j = 0; j < 2; j++) bfr[j] = lB[cur][ks * 256 + (wn * 2 + j) * 64 + lane];
#pragma unroll
      for (int i = 0; i < 4; i++)
#pragma unroll
        for (int j = 0; j < 2; j++)
          acc[i][j] = __builtin_amdgcn_mfma_f32_16x16x32_bf16(af[i], bfr[j], acc[i][j], 0, 0, 0);
    }
    if (more) VMB(6); else VMB(0);
    cur = (cur == 2) ? 0 : cur + 1;
    pf = (pf == 2) ? 0 : pf + 1;
  }
  // epilogue: C/D layout col=lane&15, row=quad*4+reg
  if (CSTORE == 0) {
    short* Cp = (short*)C0 + (long long)blockIdx.z * sC;
#pragma unroll
    for (int i = 0; i < 4; i++)
#pragma unroll
      for (int j = 0; j < 2; j++) {
        int gn = n0 + (wn * 2 + j) * 16 + l16;
#pragma unroll
        for (int rg = 0; rg < 4; rg++) {
          int gm = m0 + (wm * 4 + i) * 16 + quad * 4 + rg;
          Cp[(long long)gm * ldc + gn] = f2bf(acc[i][j][rg]);
        }
      }
  } else {
    if (*flag) {
      float* Cp = (float*)C0 + (long long)blockIdx.z * sC;
#pragma unroll
      for (int i = 0; i < 4; i++)
#pragma unroll
        for (int j = 0; j < 2; j++) {
          int gn = n0 + (wn * 2 + j) * 16 + l16;
#pragma unroll
          for (int rg = 0; rg < 4; rg++) {
            int gm = m0 + (wm * 4 + i) * 16 + quad * 4 + rg;
            Cp[(long long)gm * ldc + gn] = acc[i][j][rg];
          }
        }
    } else {
      short* Cp = (short*)C0 + (long long)blockIdx.z * sC;
#pragma unroll
      for (int i = 0; i < 4; i++)
#pragma unroll
        for (int j = 0; j < 2; j++) {
          int gn = n0 + (wn * 2 + j) * 16 + l16;
#pragma unroll
          for (int rg = 0; rg < 4; rg++) {
            int gm = m0 + (wm * 4 + i) * 16 + quad * 4 + rg;
            Cp[(long long)gm * ldc + gn] = f2bf(acc[i][j][rg]);
          }
        }
    }
  }
}

// ===== split-K kv GEMM: P[z][l][d] = k[l][:] @ Wv[d][:] over K-chunk z ========
// Tile 128x64, BK=64, 3-buffer counted-vmcnt pipeline (as bt). Grid 512 blocks.
__global__ __launch_bounds__(256) void mfma_gemm_sk(
    const short* __restrict__ A0, int lda,      // k_bf [512][2048]
    const short* __restrict__ BT0, int ldb,     // Wv_bf [2048][2048]
    float* __restrict__ P, int ldc) {           // [4][512][2048] f32
  __shared__ s16x8 lA[3][1024], lB[3][512];  // 72 KB
  const int t = threadIdx.x;
  const int wave = t >> 6, lane = t & 63;
  const int quad = lane >> 4, l16 = lane & 15;
  const int wm = wave >> 1, wn = wave & 1;
  const int m0 = blockIdx.y * 128, n0 = blockIdx.x * 64;
  const int kbeg = blockIdx.z * 512;
  const int srow = lane & 15, skc = lane >> 4;
  auto stage = [&](int b, int kk) {  // 6 gload16 per lane
#pragma unroll
    for (int i = 0; i < 2; i++) {
      int sub = wave + i * 4;
      int m = sub * 16 + srow;
#pragma unroll
      for (int ks = 0; ks < 2; ks++)
        gload16(A0 + (long long)(m0 + m) * lda + kk + ks * 32 + skc * 8,
                &lA[b][ks * 512 + sub * 64]);
    }
    int mB = wave * 16 + srow;
#pragma unroll
    for (int ks = 0; ks < 2; ks++)
      gload16(BT0 + (long long)(n0 + mB) * ldb + kk + ks * 32 + skc * 8,
              &lB[b][ks * 256 + wave * 64]);
  };
  f32x4 acc[4][2];
  const f32x4 z = {0.f, 0.f, 0.f, 0.f};
#pragma unroll
  for (int i = 0; i < 4; i++)
#pragma unroll
    for (int j = 0; j < 2; j++) acc[i][j] = z;
  stage(0, kbeg);
  stage(1, kbeg + 64);
  VMB(6);
  const int NT = 8;  // 512/64
  int cur = 0, pf = 2;
  for (int tt = 0; tt < NT; ++tt) {
    const bool more = (tt + 2 < NT);
    if (more) stage(pf, kbeg + ((tt + 2) << 6));
#pragma unroll
    for (int ks = 0; ks < 2; ks++) {
      s16x8 af[4], bfr[2];
#pragma unroll
      for (int i = 0; i < 4; i++) af[i] = lA[cur][ks * 512 + (wm * 4 + i) * 64 + lane];
#pragma unroll
      for (int j = 0; j < 2; j++) bfr[j] = lB[cur][ks * 256 + (wn * 2 + j) * 64 + lane];
#pragma unroll
      for (int i = 0; i < 4; i++)
#pragma unroll
        for (int j = 0; j < 2; j++)
          acc[i][j] = __builtin_amdgcn_mfma_f32_16x16x32_bf16(af[i], bfr[j], acc[i][j], 0, 0, 0);
    }
    if (more) VMB(6); else VMB(0);
    cur = (cur == 2) ? 0 : cur + 1;
    pf = (pf == 2) ? 0 : pf + 1;
  }
  float* Cp = P + (long long)blockIdx.z * kML * kDM;
#pragma unroll
  for (int i = 0; i < 4; i++)
#pragma unroll
    for (int j = 0; j < 2; j++) {
      int gn = n0 + (wn * 2 + j) * 16 + l16;
#pragma unroll
      for (int rg = 0; rg < 4; rg++) {
        int gm = m0 + (wm * 4 + i) * 16 + quad * 4 + rg;
        Cp[(long long)gm * ldc + gn] = acc[i][j][rg];
      }
    }
}

// reduce 4 f32 partials [z][l][d] -> kvT bf16 [d][l] (LDS transpose)
__global__ __launch_bounds__(256) void reduceT_kernel(const float* __restrict__ P,
                                                      short* __restrict__ kvT) {
  __shared__ float tile[64][65];
  const int bd = blockIdx.x, bl = blockIdx.y;  // 32 x 8
  const int tx = threadIdx.x & 63, ty = threadIdx.x >> 6;
  for (int i = ty; i < 64; i += 4) {
    int l = bl * 64 + i, d = bd * 64 + tx;
    float s = 0.f;
#pragma unroll
    for (int z = 0; z < 4; z++) s += P[((long long)z * kML + l) * kDM + d];
    tile[i][tx] = s;
  }
  __syncthreads();
  for (int i = ty; i < 64; i += 4) {
    int d = bd * 64 + i, l = bl * 64 + tx;
    kvT[(long long)d * kML + l] = f2bf(tile[tx][i]);
  }
}

// ===== split-B GEMM with SPLIT OUTPUT ==========================================
// Tile 64x64, BK=32, 3-buffer counted-vmcnt(3) pipeline. Grid 512. LDS 36 KB.
__global__ __launch_bounds__(256) void mfma_gemm_bt2(
    const short* __restrict__ A0, int lda,
    const short* __restrict__ BTh, const short* __restrict__ BTl, int ldb,
    short* __restrict__ Ch, short* __restrict__ Cl, int ldc, int K) {
  __shared__ s16x8 lA[3][256], lBh[3][256], lBl[3][256];  // 36 KB
  const int t = threadIdx.x;
  const int wave = t >> 6, lane = t & 63;
  const int quad = lane >> 4, l16 = lane & 15;
  const int wm = wave >> 1, wn = wave & 1;
  const int m0 = blockIdx.y * 64, n0 = blockIdx.x * 64;
  const int srow = lane & 15, skc = lane >> 4;
  auto stage = [&](int b, int kk) {  // 3 gload16 per lane
    int m = wave * 16 + srow;
    gload16(A0 + (long long)(m0 + m) * lda + kk + skc * 8, &lA[b][wave * 64]);
    gload16(BTh + (long long)(n0 + m) * ldb + kk + skc * 8, &lBh[b][wave * 64]);
    gload16(BTl + (long long)(n0 + m) * ldb + kk + skc * 8, &lBl[b][wave * 64]);
  };
  f32x4 acc[2][2];
  const f32x4 z = {0.f, 0.f, 0.f, 0.f};
#pragma unroll
  for (int i = 0; i < 2; i++)
#pragma unroll
    for (int j = 0; j < 2; j++) acc[i][j] = z;
  stage(0, 0);
  stage(1, 32);
  VMB(3);
  const int NT = K >> 5;
  int cur = 0, pf = 2;
  for (int tt = 0; tt < NT; ++tt) {
    const bool more = (tt + 2 < NT);
    if (more) stage(pf, (tt + 2) << 5);
    s16x8 af[2], bh[2], bl[2];
#pragma unroll
    for (int i = 0; i < 2; i++) af[i] = lA[cur][(wm * 2 + i) * 64 + lane];
#pragma unroll
    for (int j = 0; j < 2; j++) {
      bh[j] = lBh[cur][(wn * 2 + j) * 64 + lane];
      bl[j] = lBl[cur][(wn * 2 + j) * 64 + lane];
    }
#pragma unroll
    for (int i = 0; i < 2; i++)
#pragma unroll
      for (int j = 0; j < 2; j++) {
        acc[i][j] = __builtin_amdgcn_mfma_f32_16x16x32_bf16(af[i], bh[j], acc[i][j], 0, 0, 0);
        acc[i][j] = __builtin_amdgcn_mfma_f32_16x16x32_bf16(af[i], bl[j], acc[i][j], 0, 0, 0);
      }
    if (more) VMB(3); else VMB(0);
    cur = (cur == 2) ? 0 : cur + 1;
    pf = (pf == 2) ? 0 : pf + 1;
  }
#pragma unroll
  for (int i = 0; i < 2; i++)
#pragma unroll
    for (int j = 0; j < 2; j++) {
      int gn = n0 + (wn * 2 + j) * 16 + l16;
#pragma unroll
      for (int rg = 0; rg < 4; rg++) {
        int gm = m0 + (wm * 2 + i) * 16 + quad * 4 + rg;
        float v = acc[i][j][rg];
        short hb = f2bf(v);
        Ch[(long long)gm * ldc + gn] = hb;
        Cl[(long long)gm * ldc + gn] = f2bf(v - bf2f(hb));
      }
    }
}

// ===== fused r-GEMM: ctx[q][h*128+d'] = sum_n r(h,q,n) * valuesT[h*128+d'][n] ===
// Tile 64 q-rows x 128 d-cols, BK=32, 3-buffer pipeline (vmcnt(4)+lgkmcnt(0)).
// mu/sigma INLINED: each block computes its 64 rows' mu,s2 from q . kw directly
// (4-lane quad reduce) -- removes the musig dispatch. r generated on the fly
// (split rh+rl, SWZ-swizzled ds_write staging); VT via global_load_lds.
// 3 MFMA passes: rh*VTh + rh*VTl + rl*VTh. Grid 512. LDS 72 KB.
__global__ __launch_bounds__(256) void mfma_rv(
    const void* __restrict__ q, const float* __restrict__ kw,
    const int* __restrict__ flag,
    const short* __restrict__ VTh, const short* __restrict__ VTl,  // [2048][1024]
    short* __restrict__ ctx) {                                     // [2048][2048]
  __shared__ s16x8 lAh[3][256], lAl[3][256], lBh[3][512], lBl[3][512];  // 72 KB
  const int t = threadIdx.x;
  const int wave = t >> 6, lane = t & 63;
  const int quad = lane >> 4, l16 = lane & 15;
  const int wm = wave >> 1, wn = wave & 1;
  const int h = blockIdx.z;
  const int m0 = blockIdx.y * 64;  // q-rows within head
  const int r0 = t >> 2, kc = t & 3;  // r0 in [0,64): one row per 4-lane quad
  const int srow = lane & 15, skc = lane >> 4;
  const long long voff = (long long)h * kD * kNB;
  const int row = h * kQL + m0 + r0;
  // ---- inlined musig: mu, sigma^2 for this row ----
  float a = 0.f, b = 0.f;
  {
    const bool f32q = (*flag != 0);
    const float* kmu = kw + h * kD;
    const float* ksg = kw + kDM + h * kD;
    if (f32q) {
      const float* qrow = (const float*)q + (long long)row * kD;
      for (int jj = kc * 32; jj < kc * 32 + 32; jj++) {
        float qv = qrow[jj];
        a += qv * kmu[jj]; b += qv * ksg[jj];
      }
    } else {
      const short* qrow = (const short*)q + (long long)row * kD;
      for (int jj = kc * 32; jj < kc * 32 + 32; jj++) {
        float qv = bf2f(qrow[jj]);
        a += qv * kmu[jj]; b += qv * ksg[jj];
      }
    }
    a += __shfl_xor(a, 1); a += __shfl_xor(a, 2);
    b += __shfl_xor(b, 1); b += __shfl_xor(b, 2);
  }
  const float inv_sqrt_d = 0.08838834764831845f;
  const float zm = a * inv_sqrt_d, zs = b * inv_sqrt_d;
  const float m_ = 1.f / (1.f + __expf(-zm));
  const float sp = (zs > 20.f) ? zs : log1pf(__expf(zs));
  const float s2 = fmaxf(sp, 1e-4f);
  float ivs[2], cof[2];
  ivs[0] = rsqrtf(s2 + 2.5e-5f);  // b_sigma = 0.005 (even n)
  ivs[1] = rsqrtf(s2 + 1e-4f);    // b_sigma = 0.01  (odd n)
  cof[0] = 0.3989422804014327f * ivs[0];
  cof[1] = 0.3989422804014327f * ivs[1];
  const int cidx = SWZ((r0 >> 4) * 64 + kc * 16 + (r0 & 15));
  auto stageB = [&](int bb, int kk) {  // 4 gload16 per lane
#pragma unroll
    for (int i = 0; i < 2; i++) {
      int sub = wave + i * 4;  // B subtiles 0..7 (128 d-cols)
      int m = sub * 16 + srow;
      gload16(VTh + voff + (long long)m * kNB + kk + skc * 8, &lBh[bb][sub * 64]);
      gload16(VTl + voff + (long long)m * kNB + kk + skc * 8, &lBl[bb][sub * 64]);
    }
  };
  auto stageA = [&](int bb, int kk) {  // 2 ds_write per lane (swizzled slots)
    s16x8 hv, lv;
#pragma unroll
    for (int jj = 0; jj < 8; jj++) {
      int n = kk + kc * 8 + jj;
      float bmu = (float)(n >> 1) * (1.f / 511.f);
      int p = jj & 1;  // parity of n (kk, kc*8 even)
      float tt = (bmu - m_) * ivs[p];
      float v = cof[p] * __expf(-0.5f * tt * tt);
      short hb = f2bf(v);
      hv[jj] = hb;
      lv[jj] = f2bf(v - bf2f(hb));
    }
    lAh[bb][cidx] = hv;
    lAl[bb][cidx] = lv;
  };
  f32x4 acc[2][4];
  const f32x4 z = {0.f, 0.f, 0.f, 0.f};
#pragma unroll
  for (int i = 0; i < 2; i++)
#pragma unroll
    for (int j = 0; j < 4; j++) acc[i][j] = z;
  stageB(0, 0);
  stageA(0, 0);
  stageB(1, 32);
  stageA(1, 32);
  VMLB(4);
  const int NT = kNB >> 5;  // 32
  int cur = 0, pf = 2;
  for (int tt = 0; tt < NT; ++tt) {
    const bool more = (tt + 2 < NT);
    if (more) {
      stageB(pf, (tt + 2) << 5);   // async loads issued first
      stageA(pf, (tt + 2) << 5);   // ds_writes precede this iter's ds_reads (in-order DS)
    }
    s16x8 ah[2], al[2], bh[4], bl[4];
#pragma unroll
    for (int i = 0; i < 2; i++) {
      ah[i] = lAh[cur][SWZ((wm * 2 + i) * 64 + lane)];
      al[i] = lAl[cur][SWZ((wm * 2 + i) * 64 + lane)];
    }
#pragma unroll
    for (int j = 0; j < 4; j++) {
      bh[j] = lBh[cur][(wn * 4 + j) * 64 + lane];
      bl[j] = lBl[cur][(wn * 4 + j) * 64 + lane];
    }
#pragma unroll
    for (int i = 0; i < 2; i++)
#pragma unroll
      for (int j = 0; j < 4; j++) {
        acc[i][j] = __builtin_amdgcn_mfma_f32_16x16x32_bf16(ah[i], bh[j], acc[i][j], 0, 0, 0);
        acc[i][j] = __builtin_amdgcn_mfma_f32_16x16x32_bf16(ah[i], bl[j], acc[i][j], 0, 0, 0);
        acc[i][j] = __builtin_amdgcn_mfma_f32_16x16x32_bf16(al[i], bh[j], acc[i][j], 0, 0, 0);
      }
    if (more) VMLB(4); else VMLB(0);
    cur = (cur == 2) ? 0 : cur + 1;
    pf = (pf == 2) ? 0 : pf + 1;
  }
  short* Cp = ctx + h * kD;
#pragma unroll
  for (int i = 0; i < 2; i++)
#pragma unroll
    for (int j = 0; j < 4; j++) {
      int gn = (wn * 4 + j) * 16 + l16;
#pragma unroll
      for (int rg = 0; rg < 4; rg++) {
        int gm = m0 + (wm * 2 + i) * 16 + quad * 4 + rg;
        Cp[(long long)gm * kDM + gn] = f2bf(acc[i][j][rg]);
      }
    }
}

extern "C" void kernel_launch(void* const* d_in, const int* in_sizes, int n_in,
                              void* d_out, int out_size, void* d_ws, size_t ws_size,
                              hipStream_t stream) {
  (void)in_sizes; (void)n_in; (void)out_size; (void)ws_size;
  const void* kmem = d_in[0];
  const void* q    = d_in[1];
  const void* Wk   = d_in[2];
  const void* Wv   = d_in[3];
  const void* Wo   = d_in[4];
  const void* wmu  = d_in[5];
  const void* wsg  = d_in[6];

  // ---- workspace layout (~32.5 MB total) ----
  char* ws = (char*)d_ws;
  short* k_bf  = (short*)ws;                          // [512][2048] bf16, 2 MB
  short* kvT   = (short*)(ws + ((size_t)2 << 20));    // [2048][512] bf16, 2 MB
  short* Wv_bf = (short*)(ws + ((size_t)4 << 20));    // [2048][2048] bf16, 8 MB (dead after kv)
  short* Wo_bf = Wv_bf;                               // overlay AFTER kv GEMM
  float* Pbuf  = (float*)(ws + ((size_t)12 << 20));   // [4][512][2048] f32, 16 MB
  short* VTh   = (short*)(ws + ((size_t)12 << 20));   // [2048][1024] bf16, 4 MB (overlays Pbuf)
  short* VTl   = (short*)(ws + ((size_t)16 << 20));   // [2048][1024] bf16, 4 MB
  short* ctx   = (short*)(ws + ((size_t)20 << 20));   // [2048][2048] bf16, 8 MB
  float* tail  = (float*)(ws + ((size_t)28 << 20));
  float* gw    = tail;                 // 2*512
  float* bw    = gw + 2 * kML;         // 2*2048
  float* kw    = bw + 2 * kDM;         // 2*2048
  int*   flag  = (int*)(kw + 2 * kDM);
  float* gtffall = (float*)(ws + ((size_t)28 << 20) + ((size_t)1 << 19));  // 2 MB @28.5
  short* ghfall  = (short*)(ws + ((size_t)30 << 20) + ((size_t)1 << 19));  // 1 MB @30.5
  short* glfall  = (short*)(ws + ((size_t)31 << 20) + ((size_t)1 << 19));  // 1 MB @31.5

  const float* GtTf = g_init.d_GtTf;
  if (!GtTf) {
    const void* src = g_init.h_GtTf_pinned ? (const void*)g_init.h_GtTf_pinned
                                           : (const void*)g_init.h_GtTf.data();
    hipMemcpyAsync(gtffall, src, (size_t)kNB * kML * 4, hipMemcpyHostToDevice, stream);
    GtTf = gtffall;
  }
  const short* Gh = (const short*)g_init.d_Gth;
  if (!Gh) {
    const void* src = g_init.h_Gth_pinned ? (const void*)g_init.h_Gth_pinned
                                          : (const void*)g_init.h_Gth.data();
    hipMemcpyAsync(ghfall, src, (size_t)kNB * kML * 2, hipMemcpyHostToDevice, stream);
    Gh = ghfall;
  }
  const short* Gl = (const short*)g_init.d_Gtl;
  if (!Gl) {
    const void* src = g_init.h_Gtl_pinned ? (const void*)g_init.h_Gtl_pinned
                                          : (const void*)g_init.h_Gtl.data();
    hipMemcpyAsync(glfall, src, (size_t)kNB * kML * 2, hipMemcpyHostToDevice, stream);
    Gl = glfall;
  }

  // 1) fused dtype-detect + k/Wv -> bf16 (flag published for downstream)
  prep_kernel<<<5120, 256, 0, stream>>>((const unsigned short*)q, kmem, Wv,
                                        k_bf, Wv_bf, flag);

  // 2) exact f32 mu/sigma inputs: gw -> bw (atomic-free) -> kw
  gw_kernel<<<kML, 256, 0, stream>>>(GtTf, wmu, wsg, gw, flag);
  bwk_kernel<<<kDM / 256, 256, 0, stream>>>(kmem, gw, bw, flag);
  kw_kernel<<<kDM, 256, 0, stream>>>(Wk, bw, kw, flag);

  // 3) kv GEMM split-K=4: P[z][l][d] partials. 128x64 tiles -> 512 blocks (2/CU).
  mfma_gemm_sk<<<dim3(kDM / 64, kML / 128, 4), 256, 0, stream>>>(
      k_bf, kDM, Wv_bf, kDM, Pbuf, kDM);
  // reduce partials -> kvT[d][l] bf16 (single f2bf rounding)
  reduceT_kernel<<<dim3(kDM / 64, kML / 64), 256, 0, stream>>>(Pbuf, kvT);

  // 4) Wo -> bf16 (overlays Wv_bf, dead after kv GEMM)
  conv_bf16<<<(kDM * kDM / 4 + 255) / 256, 256, 0, stream>>>(Wo, Wo_bf, kDM * kDM / 4, flag);

  // 5) valuesT[d][n] = sum_l kvT[d][l] * G[l][n]  (split G in, split VT out)
  mfma_gemm_bt2<<<dim3(kNB / 64, kDM / 64, 1), 256, 0, stream>>>(
      kvT, kML, Gh, Gl, kML, VTh, VTl, kNB, kML);

  // 6) ctx = r @ valuesT (mu/sigma inlined; 3-pass split x split)
  mfma_rv<<<dim3(1, kQL / 64, kH), 256, 0, stream>>>(q, kw, flag, VTh, VTl, ctx);

  // 7) out = ctx @ Wo^T  (runtime out dtype). 128x64 tiles -> grid (32, 16) = 512.
  mfma_gemm_bt<2><<<dim3(kDM / 64, kQL / 128, 1), 256, 0, stream>>>(
      ctx, kDM, 0, Wo_bf, kDM, 0, d_out, kDM, 0, kDM, flag);
}

// Round 14
// 257.567 us; speedup vs baseline: 1.1849x; 1.1849x over previous
//
#include <hip/hip_runtime.h>
#include <hip/hip_bf16.h>
#include <vector>
#include <cmath>
#include <cstring>

using bf16 = __hip_bfloat16;
typedef short s16x8 __attribute__((ext_vector_type(8)));
typedef float f32x4 __attribute__((ext_vector_type(4)));

static constexpr int kH = 16, kD = 128, kNB = 1024, kML = 512, kQL = 2048, kDM = 2048;

// counted-vmcnt barrier (m201 pattern)
#define VMB(N) do { asm volatile("s_waitcnt vmcnt(" #N ")" ::: "memory"); \
                    __builtin_amdgcn_s_barrier(); \
                    asm volatile("" ::: "memory"); } while (0)
#define VMLB(N) do { asm volatile("s_waitcnt vmcnt(" #N ") lgkmcnt(0)" ::: "memory"); \
                     __builtin_amdgcn_s_barrier(); \
                     asm volatile("" ::: "memory"); } while (0)
// bank-conflict swizzle for VALU-staged (ds_write) LDS tiles; involution,
// applied identically on write and read. NOT used on global_load_lds tiles.
#define SWZ(c) ((c) ^ (((c) >> 4) & 3))

// ================= host precompute of Gt (input-independent) =================
static void compute_Gt_host(float* Gt) {
  const int n = kNB, P = 2 * kML;
  std::vector<double> F((size_t)n * P), A((size_t)n * n), pos(P);
  const double shift = 1.0 / (double)P;
  const double p0 = -0.5 + shift, p1 = 1.5 - shift;
  for (int i = 0; i < P; i++) pos[i] = p0 + (p1 - p0) * (double)i / (double)(P - 1);
  const double c0 = 0.3989422804014327;
  std::vector<int> lo(n), hi(n);
  for (int b = 0; b < n; b++) {
    double mu = (double)(b >> 1) / 511.0;
    double sg = (b & 1) ? 0.01 : 0.005;
    double c = c0 / sg;
    double* Fb = &F[(size_t)b * P];
    for (int i = 0; i < P; i++) { double t = (pos[i] - mu) / sg; Fb[i] = c * exp(-0.5 * t * t); }
    int l = 0; while (l < P - 1 && pos[l] < mu - 14.0 * sg) l++;
    int h = P - 1; while (h > 0 && pos[h] > mu + 14.0 * sg) h--;
    lo[b] = l; hi[b] = h;
  }
  for (int i = 0; i < n; i++) {
    const double* fi = &F[(size_t)i * P];
    for (int j = 0; j <= i; j++) {
      const double* fj = &F[(size_t)j * P];
      int a = lo[i] > lo[j] ? lo[i] : lo[j];
      int b2 = hi[i] < hi[j] ? hi[i] : hi[j];
      double s = 0.0;
      for (int k2 = a; k2 <= b2; k2++) s += fi[k2] * fj[k2];
      A[(size_t)i * n + j] = s;
      if (i != j) A[(size_t)j * n + i] = s;
    }
    A[(size_t)i * n + i] += 0.5;
  }
  for (int j = 0; j < n; j++) {  // Cholesky
    double* Aj = &A[(size_t)j * n];
    double d = Aj[j];
    for (int k2 = 0; k2 < j; k2++) d -= Aj[k2] * Aj[k2];
    d = std::sqrt(d); Aj[j] = d;
    double inv = 1.0 / d;
    for (int i = j + 1; i < n; i++) {
      double* Ai = &A[(size_t)i * n];
      double s = Ai[j];
      for (int k2 = 0; k2 < j; k2++) s -= Ai[k2] * Aj[k2];
      Ai[j] = s * inv;
    }
  }
  for (int i = 0; i < n; i++) {  // L Y = F
    double* yi = &F[(size_t)i * P];
    const double* Ai = &A[(size_t)i * n];
    for (int k2 = 0; k2 < i; k2++) {
      double lik = Ai[k2];
      const double* yk = &F[(size_t)k2 * P];
      for (int t = 0; t < P; t++) yi[t] -= lik * yk[t];
    }
    double inv = 1.0 / Ai[i];
    for (int t = 0; t < P; t++) yi[t] *= inv;
  }
  for (int i = n - 1; i >= 0; i--) {  // L^T X = Y
    double* xi = &F[(size_t)i * P];
    for (int k2 = i + 1; k2 < n; k2++) {
      double lki = A[(size_t)k2 * n + i];
      const double* xk = &F[(size_t)k2 * P];
      for (int t = 0; t < P; t++) xi[t] -= lki * xk[t];
    }
    double inv = 1.0 / A[(size_t)i * n + i];
    for (int t = 0; t < P; t++) xi[t] *= inv;
  }
  for (int b = 0; b < n; b++)
    for (int l = 0; l < kML; l++)
      Gt[(size_t)b * kML + l] = (float)F[(size_t)b * P + (kML / 2) + l];
}

static unsigned short f2bf_host(float x) {
  unsigned u; std::memcpy(&u, &x, 4);
  unsigned r = (u + 0x7FFFu + ((u >> 16) & 1u)) >> 16;
  return (unsigned short)r;
}
static float bf2f_host(unsigned short b) {
  unsigned u = ((unsigned)b) << 16; float f; std::memcpy(&f, &u, 4); return f;
}

namespace {
struct Init {
  float* d_GtTf = nullptr;           // f32 GtT[l][n]  [512][1024]
  unsigned short* d_Gth = nullptr;   // bf16-hi Gt[n][l]  [1024][512]
  unsigned short* d_Gtl = nullptr;   // bf16-lo Gt[n][l]  [1024][512]
  float* h_GtTf_pinned = nullptr;
  unsigned short* h_Gth_pinned = nullptr;
  unsigned short* h_Gtl_pinned = nullptr;
  std::vector<float> h_GtTf;
  std::vector<unsigned short> h_Gth, h_Gtl;
  Init() {
    std::vector<float> h_Gt((size_t)kNB * kML);
    compute_Gt_host(h_Gt.data());
    h_GtTf.resize(h_Gt.size());
    h_Gth.resize(h_Gt.size());
    h_Gtl.resize(h_Gt.size());
    for (int n = 0; n < kNB; n++)
      for (int l = 0; l < kML; l++) {
        float v = h_Gt[(size_t)n * kML + l];
        h_GtTf[(size_t)l * kNB + n] = v;
        unsigned short hb = f2bf_host(v);
        h_Gth[(size_t)n * kML + l] = hb;
        h_Gtl[(size_t)n * kML + l] = f2bf_host(v - bf2f_host(hb));
      }
    const size_t fb = h_Gt.size() * 4, bb = h_Gt.size() * 2;
    if (hipMalloc((void**)&d_GtTf, fb) == hipSuccess) {
      if (hipMemcpy(d_GtTf, h_GtTf.data(), fb, hipMemcpyHostToDevice) != hipSuccess) { hipFree(d_GtTf); d_GtTf = nullptr; }
    }
    if (hipMalloc((void**)&d_Gth, bb) == hipSuccess) {
      if (hipMemcpy(d_Gth, h_Gth.data(), bb, hipMemcpyHostToDevice) != hipSuccess) { hipFree(d_Gth); d_Gth = nullptr; }
    }
    if (hipMalloc((void**)&d_Gtl, bb) == hipSuccess) {
      if (hipMemcpy(d_Gtl, h_Gtl.data(), bb, hipMemcpyHostToDevice) != hipSuccess) { hipFree(d_Gtl); d_Gtl = nullptr; }
    }
    if (!d_GtTf && hipHostMalloc((void**)&h_GtTf_pinned, fb, 0) == hipSuccess)
      std::memcpy(h_GtTf_pinned, h_GtTf.data(), fb);
    if (!d_Gth && hipHostMalloc((void**)&h_Gth_pinned, bb, 0) == hipSuccess)
      std::memcpy(h_Gth_pinned, h_Gth.data(), bb);
    if (!d_Gtl && hipHostMalloc((void**)&h_Gtl_pinned, bb, 0) == hipSuccess)
      std::memcpy(h_Gtl_pinned, h_Gtl.data(), bb);
  }
};
Init g_init;
}

// ================= device helpers =================
__device__ inline short f2bf(float x) {
  unsigned u = __float_as_uint(x);
  unsigned r = (u + 0x7FFFu + ((u >> 16) & 1u)) >> 16;
  return (short)r;
}
__device__ inline float bf2f(short b) {
  return __uint_as_float(((unsigned)(unsigned short)b) << 16);
}

// async global->LDS, 16 B per lane; LDS dest is wave-uniform base + lane*16.
__device__ inline void gload16(const void* g, void* l) {
  __builtin_amdgcn_global_load_lds(
      (__attribute__((address_space(1))) void*)(g),
      (__attribute__((address_space(3))) void*)(l),
      16, 0, 0);
}

// local dtype detection: read first 512 ushorts of q; exponent-field >= 0x98
// occurs (w.h.p.) iff data is f32 (mantissa low-halves are ~uniform).
__device__ inline int detect_local(const unsigned short* q) {
  int bad = 0;
  for (int i = threadIdx.x; i < 512; i += 256) {
    int e = (q[i] >> 7) & 0xFF;
    if (e >= 0x98) bad = 1;
  }
  __shared__ int s[256];
  s[threadIdx.x] = bad; __syncthreads();
  for (int k2 = 128; k2 > 0; k2 >>= 1) {
    if (threadIdx.x < k2) s[threadIdx.x] |= s[threadIdx.x + k2];
    __syncthreads();
  }
  return s[0];
}

// ===== fused prep: dtype detect + convert k/Wv to bf16 + zero bw + flag =======
// grid: [0,1024) -> k (512x2048), [1024,5120) -> Wv (2048x2048). 4 elems/thread.
// Block 0 additionally zeroes bw (4096 f32) for the downstream atomic bwk.
__global__ __launch_bounds__(256) void prep_kernel(const unsigned short* __restrict__ q,
                                                   const void* __restrict__ kin,
                                                   const void* __restrict__ Wv,
                                                   short* __restrict__ k_bf,
                                                   short* __restrict__ Wv_bf,
                                                   float* __restrict__ bw,
                                                   int* __restrict__ flag) {
  const int f32 = detect_local(q);
  if (blockIdx.x == 0) {
    if (threadIdx.x == 0) *flag = f32;
    for (int i = threadIdx.x; i < 2 * kDM; i += 256) bw[i] = 0.f;
  }
  const void* src; short* dst; int i;
  if (blockIdx.x < 1024) { src = kin; dst = k_bf; i = blockIdx.x * 256 + threadIdx.x; }
  else { src = Wv; dst = Wv_bf; i = (blockIdx.x - 1024) * 256 + threadIdx.x; }
  if (f32) {
    float4 v = ((const float4*)src)[i];
    short4 o; o.x = f2bf(v.x); o.y = f2bf(v.y); o.z = f2bf(v.z); o.w = f2bf(v.w);
    ((short4*)dst)[i] = o;
  } else {
    ((short4*)dst)[i] = ((const short4*)src)[i];
  }
}

// elementwise convert (f32|bf16 in) -> bf16, 4 elems/thread (used for Wo)
__global__ __launch_bounds__(256) void conv_bf16(const void* __restrict__ in,
                                                 short* __restrict__ out, int n4,
                                                 const int* __restrict__ flag) {
  int i = blockIdx.x * 256 + threadIdx.x;
  if (i >= n4) return;
  if (*flag) {
    float4 v = ((const float4*)in)[i];
    short4 o; o.x = f2bf(v.x); o.y = f2bf(v.y); o.z = f2bf(v.z); o.w = f2bf(v.w);
    ((short4*)out)[i] = o;
  } else {
    ((short4*)out)[i] = ((const short4*)in)[i];
  }
}

// ===== exact f32 mu/sigma path =====
__global__ __launch_bounds__(256) void gw_kernel(const float* __restrict__ GtT,
                                                 const void* __restrict__ wmu,
                                                 const void* __restrict__ wsg,
                                                 float* __restrict__ gw,
                                                 const int* __restrict__ flag) {
  const bool f32 = (*flag != 0);
  const int l = blockIdx.x, t = threadIdx.x;
  const float* row = GtT + (long long)l * kNB;
  float a = 0.f, b = 0.f;
  for (int n = t; n < kNB; n += 256) {
    float g = row[n];
    float wm_ = f32 ? ((const float*)wmu)[n] : bf2f(((const short*)wmu)[n]);
    float ws_ = f32 ? ((const float*)wsg)[n] : bf2f(((const short*)wsg)[n]);
    a += g * wm_; b += g * ws_;
  }
  __shared__ float red[2][256];
  red[0][t] = a; red[1][t] = b;
  __syncthreads();
  for (int s = 128; s > 0; s >>= 1) {
    if (t < s) { red[0][t] += red[0][t + s]; red[1][t] += red[1][t + s]; }
    __syncthreads();
  }
  if (t == 0) { gw[l] = red[0][0]; gw[kML + l] = red[1][0]; }
}

// bw[j] += sum_{l in chunk} k[l][j] * gw[l]  -- grid (8 j-blocks, 16 l-chunks),
// coalesced row reads, atomic combine (bw pre-zeroed by prep_kernel).
__global__ __launch_bounds__(256) void bwk_kernel(const void* __restrict__ kin,
                                                  const float* __restrict__ gw,
                                                  float* __restrict__ bw,
                                                  const int* __restrict__ flag) {
  const bool f32 = (*flag != 0);
  int j = blockIdx.x * 256 + threadIdx.x;
  int l0 = blockIdx.y * 32;
  float a = 0.f, b = 0.f;
  for (int l = l0; l < l0 + 32; l++) {
    float kv = f32 ? ((const float*)kin)[(long long)l * kDM + j]
                   : bf2f(((const short*)kin)[(long long)l * kDM + j]);
    a += kv * gw[l]; b += kv * gw[kML + l];
  }
  atomicAdd(&bw[j], a);
  atomicAdd(&bw[kDM + j], b);
}

__global__ __launch_bounds__(256) void kw_kernel(const void* __restrict__ Wk,
                                                 const float* __restrict__ bw,
                                                 float* __restrict__ kw,
                                                 const int* __restrict__ flag) {
  const bool f32 = (*flag != 0);
  int i = blockIdx.x;
  float smu = 0.f, ssg = 0.f;
  if (f32) {
    const float* row = (const float*)Wk + (long long)i * kDM;
    for (int j = threadIdx.x; j < kDM; j += 256) { float w = row[j]; smu += w * bw[j]; ssg += w * bw[kDM + j]; }
  } else {
    const short* row = (const short*)Wk + (long long)i * kDM;
    for (int j = threadIdx.x; j < kDM; j += 256) { float w = bf2f(row[j]); smu += w * bw[j]; ssg += w * bw[kDM + j]; }
  }
  __shared__ float red[2][256];
  red[0][threadIdx.x] = smu; red[1][threadIdx.x] = ssg;
  __syncthreads();
  for (int s = 128; s > 0; s >>= 1) {
    if (threadIdx.x < (unsigned)s) {
      red[0][threadIdx.x] += red[0][threadIdx.x + s];
      red[1][threadIdx.x] += red[1][threadIdx.x + s];
    }
    __syncthreads();
  }
  if (threadIdx.x == 0) { kw[i] = red[0][0]; kw[kDM + i] = red[1][0]; }
}

// ===== MFMA GEMM: C[M,N] = A[M,K] @ BT[N,K]^T (bf16 in, f32 acc) ===============
// Tile 128x64, BK=64. 3-buffer pipeline, prefetch distance 2, counted vmcnt(6).
// LDS 72 KB -> 2 blocks/CU (grid 512). CSTORE: 0 = bf16; 2 = runtime dtype.
template <int CSTORE>
__global__ __launch_bounds__(256) void mfma_gemm_bt(
    const short* __restrict__ A0, int lda, long long sA,
    const short* __restrict__ BT0, int ldb, long long sB,
    void* __restrict__ C0, int ldc, long long sC,
    int K, const int* __restrict__ flag) {
  __shared__ s16x8 lA[3][1024];  // [buf][ks*512 + sub*64 + lane]
  __shared__ s16x8 lB[3][512];   // [buf][ks*256 + sub*64 + lane]
  const short* A = A0 + (long long)blockIdx.z * sA;
  const short* BT = BT0 + (long long)blockIdx.z * sB;
  const int t = threadIdx.x;
  const int wave = t >> 6, lane = t & 63;
  const int quad = lane >> 4, l16 = lane & 15;
  const int wm = wave >> 1, wn = wave & 1;
  const int m0 = blockIdx.y * 128, n0 = blockIdx.x * 64;
  const int srow = lane & 15, skc = lane >> 4;
  auto stage = [&](int b, int kk) {              // 6 gload16 per lane
#pragma unroll
    for (int i = 0; i < 2; i++) {
      int sub = wave + i * 4;         // A subtiles 0..7
      int m = sub * 16 + srow;
#pragma unroll
      for (int ks = 0; ks < 2; ks++)
        gload16(A + (long long)(m0 + m) * lda + kk + ks * 32 + skc * 8,
                &lA[b][ks * 512 + sub * 64]);
    }
    int mB = wave * 16 + srow;        // B subtiles 0..3, one per wave
#pragma unroll
    for (int ks = 0; ks < 2; ks++)
      gload16(BT + (long long)(n0 + mB) * ldb + kk + ks * 32 + skc * 8,
              &lB[b][ks * 256 + wave * 64]);
  };
  f32x4 acc[4][2];
  const f32x4 z = {0.f, 0.f, 0.f, 0.f};
#pragma unroll
  for (int i = 0; i < 4; i++)
#pragma unroll
    for (int j = 0; j < 2; j++) acc[i][j] = z;
  stage(0, 0);
  stage(1, 64);
  VMB(6);                       // tile 0 landed; tile 1 in flight
  const int NT = K >> 6;
  int cur = 0, pf = 2;
  for (int tt = 0; tt < NT; ++tt) {
    const bool more = (tt + 2 < NT);
    if (more) stage(pf, (tt + 2) << 6);
#pragma unroll
    for (int ks = 0; ks < 2; ks++) {
      s16x8 af[4], bfr[2];
#pragma unroll
      for (int i = 0; i < 4; i++) af[i] = lA[cur][ks * 512 + (wm * 4 + i) * 64 + lane];
#pragma unroll
      for (int j = 0; j < 2; j++) bfr[j] = lB[cur][ks * 256 + (wn * 2 + j) * 64 + lane];
#pragma unroll
      for (int i = 0; i < 4; i++)
#pragma unroll
        for (int j = 0; j < 2; j++)
          acc[i][j] = __builtin_amdgcn_mfma_f32_16x16x32_bf16(af[i], bfr[j], acc[i][j], 0, 0, 0);
    }
    if (more) VMB(6); else VMB(0);
    cur = (cur == 2) ? 0 : cur + 1;
    pf = (pf == 2) ? 0 : pf + 1;
  }
  // epilogue: C/D layout col=lane&15, row=quad*4+reg
  if (CSTORE == 0) {
    short* Cp = (short*)C0 + (long long)blockIdx.z * sC;
#pragma unroll
    for (int i = 0; i < 4; i++)
#pragma unroll
      for (int j = 0; j < 2; j++) {
        int gn = n0 + (wn * 2 + j) * 16 + l16;
#pragma unroll
        for (int rg = 0; rg < 4; rg++) {
          int gm = m0 + (wm * 4 + i) * 16 + quad * 4 + rg;
          Cp[(long long)gm * ldc + gn] = f2bf(acc[i][j][rg]);
        }
      }
  } else {
    if (*flag) {
      float* Cp = (float*)C0 + (long long)blockIdx.z * sC;
#pragma unroll
      for (int i = 0; i < 4; i++)
#pragma unroll
        for (int j = 0; j < 2; j++) {
          int gn = n0 + (wn * 2 + j) * 16 + l16;
#pragma unroll
          for (int rg = 0; rg < 4; rg++) {
            int gm = m0 + (wm * 4 + i) * 16 + quad * 4 + rg;
            Cp[(long long)gm * ldc + gn] = acc[i][j][rg];
          }
        }
    } else {
      short* Cp = (short*)C0 + (long long)blockIdx.z * sC;
#pragma unroll
      for (int i = 0; i < 4; i++)
#pragma unroll
        for (int j = 0; j < 2; j++) {
          int gn = n0 + (wn * 2 + j) * 16 + l16;
#pragma unroll
          for (int rg = 0; rg < 4; rg++) {
            int gm = m0 + (wm * 4 + i) * 16 + quad * 4 + rg;
            Cp[(long long)gm * ldc + gn] = f2bf(acc[i][j][rg]);
          }
        }
    }
  }
}

// ===== split-K kv GEMM: P[z][l][d] = k[l][:] @ Wv[d][:] over K-chunk z ========
// Tile 128x64, BK=64, 3-buffer counted-vmcnt pipeline (as bt). Grid 512 blocks.
__global__ __launch_bounds__(256) void mfma_gemm_sk(
    const short* __restrict__ A0, int lda,      // k_bf [512][2048]
    const short* __restrict__ BT0, int ldb,     // Wv_bf [2048][2048]
    float* __restrict__ P, int ldc) {           // [4][512][2048] f32
  __shared__ s16x8 lA[3][1024], lB[3][512];  // 72 KB
  const int t = threadIdx.x;
  const int wave = t >> 6, lane = t & 63;
  const int quad = lane >> 4, l16 = lane & 15;
  const int wm = wave >> 1, wn = wave & 1;
  const int m0 = blockIdx.y * 128, n0 = blockIdx.x * 64;
  const int kbeg = blockIdx.z * 512;
  const int srow = lane & 15, skc = lane >> 4;
  auto stage = [&](int b, int kk) {  // 6 gload16 per lane
#pragma unroll
    for (int i = 0; i < 2; i++) {
      int sub = wave + i * 4;
      int m = sub * 16 + srow;
#pragma unroll
      for (int ks = 0; ks < 2; ks++)
        gload16(A0 + (long long)(m0 + m) * lda + kk + ks * 32 + skc * 8,
                &lA[b][ks * 512 + sub * 64]);
    }
    int mB = wave * 16 + srow;
#pragma unroll
    for (int ks = 0; ks < 2; ks++)
      gload16(BT0 + (long long)(n0 + mB) * ldb + kk + ks * 32 + skc * 8,
              &lB[b][ks * 256 + wave * 64]);
  };
  f32x4 acc[4][2];
  const f32x4 z = {0.f, 0.f, 0.f, 0.f};
#pragma unroll
  for (int i = 0; i < 4; i++)
#pragma unroll
    for (int j = 0; j < 2; j++) acc[i][j] = z;
  stage(0, kbeg);
  stage(1, kbeg + 64);
  VMB(6);
  const int NT = 8;  // 512/64
  int cur = 0, pf = 2;
  for (int tt = 0; tt < NT; ++tt) {
    const bool more = (tt + 2 < NT);
    if (more) stage(pf, kbeg + ((tt + 2) << 6));
#pragma unroll
    for (int ks = 0; ks < 2; ks++) {
      s16x8 af[4], bfr[2];
#pragma unroll
      for (int i = 0; i < 4; i++) af[i] = lA[cur][ks * 512 + (wm * 4 + i) * 64 + lane];
#pragma unroll
      for (int j = 0; j < 2; j++) bfr[j] = lB[cur][ks * 256 + (wn * 2 + j) * 64 + lane];
#pragma unroll
      for (int i = 0; i < 4; i++)
#pragma unroll
        for (int j = 0; j < 2; j++)
          acc[i][j] = __builtin_amdgcn_mfma_f32_16x16x32_bf16(af[i], bfr[j], acc[i][j], 0, 0, 0);
    }
    if (more) VMB(6); else VMB(0);
    cur = (cur == 2) ? 0 : cur + 1;
    pf = (pf == 2) ? 0 : pf + 1;
  }
  float* Cp = P + (long long)blockIdx.z * kML * kDM;
#pragma unroll
  for (int i = 0; i < 4; i++)
#pragma unroll
    for (int j = 0; j < 2; j++) {
      int gn = n0 + (wn * 2 + j) * 16 + l16;
#pragma unroll
      for (int rg = 0; rg < 4; rg++) {
        int gm = m0 + (wm * 4 + i) * 16 + quad * 4 + rg;
        Cp[(long long)gm * ldc + gn] = acc[i][j][rg];
      }
    }
}

// reduce 4 f32 partials [z][l][d] -> kvT bf16 [d][l] (LDS transpose)
__global__ __launch_bounds__(256) void reduceT_kernel(const float* __restrict__ P,
                                                      short* __restrict__ kvT) {
  __shared__ float tile[64][65];
  const int bd = blockIdx.x, bl = blockIdx.y;  // 32 x 8
  const int tx = threadIdx.x & 63, ty = threadIdx.x >> 6;
  for (int i = ty; i < 64; i += 4) {
    int l = bl * 64 + i, d = bd * 64 + tx;
    float s = 0.f;
#pragma unroll
    for (int z = 0; z < 4; z++) s += P[((long long)z * kML + l) * kDM + d];
    tile[i][tx] = s;
  }
  __syncthreads();
  for (int i = ty; i < 64; i += 4) {
    int d = bd * 64 + i, l = bl * 64 + tx;
    kvT[(long long)d * kML + l] = f2bf(tile[tx][i]);
  }
}

// ===== split-B GEMM with SPLIT OUTPUT ==========================================
// Tile 64x64, BK=32, 3-buffer counted-vmcnt(3) pipeline. Grid 512. LDS 36 KB.
__global__ __launch_bounds__(256) void mfma_gemm_bt2(
    const short* __restrict__ A0, int lda,
    const short* __restrict__ BTh, const short* __restrict__ BTl, int ldb,
    short* __restrict__ Ch, short* __restrict__ Cl, int ldc, int K) {
  __shared__ s16x8 lA[3][256], lBh[3][256], lBl[3][256];  // 36 KB
  const int t = threadIdx.x;
  const int wave = t >> 6, lane = t & 63;
  const int quad = lane >> 4, l16 = lane & 15;
  const int wm = wave >> 1, wn = wave & 1;
  const int m0 = blockIdx.y * 64, n0 = blockIdx.x * 64;
  const int srow = lane & 15, skc = lane >> 4;
  auto stage = [&](int b, int kk) {  // 3 gload16 per lane
    int m = wave * 16 + srow;
    gload16(A0 + (long long)(m0 + m) * lda + kk + skc * 8, &lA[b][wave * 64]);
    gload16(BTh + (long long)(n0 + m) * ldb + kk + skc * 8, &lBh[b][wave * 64]);
    gload16(BTl + (long long)(n0 + m) * ldb + kk + skc * 8, &lBl[b][wave * 64]);
  };
  f32x4 acc[2][2];
  const f32x4 z = {0.f, 0.f, 0.f, 0.f};
#pragma unroll
  for (int i = 0; i < 2; i++)
#pragma unroll
    for (int j = 0; j < 2; j++) acc[i][j] = z;
  stage(0, 0);
  stage(1, 32);
  VMB(3);
  const int NT = K >> 5;
  int cur = 0, pf = 2;
  for (int tt = 0; tt < NT; ++tt) {
    const bool more = (tt + 2 < NT);
    if (more) stage(pf, (tt + 2) << 5);
    s16x8 af[2], bh[2], bl[2];
#pragma unroll
    for (int i = 0; i < 2; i++) af[i] = lA[cur][(wm * 2 + i) * 64 + lane];
#pragma unroll
    for (int j = 0; j < 2; j++) {
      bh[j] = lBh[cur][(wn * 2 + j) * 64 + lane];
      bl[j] = lBl[cur][(wn * 2 + j) * 64 + lane];
    }
#pragma unroll
    for (int i = 0; i < 2; i++)
#pragma unroll
      for (int j = 0; j < 2; j++) {
        acc[i][j] = __builtin_amdgcn_mfma_f32_16x16x32_bf16(af[i], bh[j], acc[i][j], 0, 0, 0);
        acc[i][j] = __builtin_amdgcn_mfma_f32_16x16x32_bf16(af[i], bl[j], acc[i][j], 0, 0, 0);
      }
    if (more) VMB(3); else VMB(0);
    cur = (cur == 2) ? 0 : cur + 1;
    pf = (pf == 2) ? 0 : pf + 1;
  }
#pragma unroll
  for (int i = 0; i < 2; i++)
#pragma unroll
    for (int j = 0; j < 2; j++) {
      int gn = n0 + (wn * 2 + j) * 16 + l16;
#pragma unroll
      for (int rg = 0; rg < 4; rg++) {
        int gm = m0 + (wm * 2 + i) * 16 + quad * 4 + rg;
        float v = acc[i][j][rg];
        short hb = f2bf(v);
        Ch[(long long)gm * ldc + gn] = hb;
        Cl[(long long)gm * ldc + gn] = f2bf(v - bf2f(hb));
      }
    }
}

// ===== fused r-GEMM: ctx[q][h*128+d'] = sum_n r(h,q,n) * valuesT[h*128+d'][n] ===
// Tile 64 q-rows x 128 d-cols, BK=32, 3-buffer pipeline (vmcnt(4)+lgkmcnt(0)).
// mu/sigma INLINED (4-lane quad reduce from q . kw). r generated on the fly
// (split rh+rl, SWZ-swizzled ds_write staging); VT via global_load_lds.
// 3 MFMA passes: rh*VTh + rh*VTl + rl*VTh. Grid 512. LDS 72 KB.
__global__ __launch_bounds__(256) void mfma_rv(
    const void* __restrict__ q, const float* __restrict__ kw,
    const int* __restrict__ flag,
    const short* __restrict__ VTh, const short* __restrict__ VTl,  // [2048][1024]
    short* __restrict__ ctx) {                                     // [2048][2048]
  __shared__ s16x8 lAh[3][256], lAl[3][256], lBh[3][512], lBl[3][512];  // 72 KB
  const int t = threadIdx.x;
  const int wave = t >> 6, lane = t & 63;
  const int quad = lane >> 4, l16 = lane & 15;
  const int wm = wave >> 1, wn = wave & 1;
  const int h = blockIdx.z;
  const int m0 = blockIdx.y * 64;  // q-rows within head
  const int r0 = t >> 2, kc = t & 3;  // r0 in [0,64): one row per 4-lane quad
  const int srow = lane & 15, skc = lane >> 4;
  const long long voff = (long long)h * kD * kNB;
  const int row = h * kQL + m0 + r0;
  // ---- inlined musig: mu, sigma^2 for this row ----
  float a = 0.f, b = 0.f;
  {
    const bool f32q = (*flag != 0);
    const float* kmu = kw + h * kD;
    const float* ksg = kw + kDM + h * kD;
    if (f32q) {
      const float* qrow = (const float*)q + (long long)row * kD;
      for (int jj = kc * 32; jj < kc * 32 + 32; jj++) {
        float qv = qrow[jj];
        a += qv * kmu[jj]; b += qv * ksg[jj];
      }
    } else {
      const short* qrow = (const short*)q + (long long)row * kD;
      for (int jj = kc * 32; jj < kc * 32 + 32; jj++) {
        float qv = bf2f(qrow[jj]);
        a += qv * kmu[jj]; b += qv * ksg[jj];
      }
    }
    a += __shfl_xor(a, 1); a += __shfl_xor(a, 2);
    b += __shfl_xor(b, 1); b += __shfl_xor(b, 2);
  }
  const float inv_sqrt_d = 0.08838834764831845f;
  const float zm = a * inv_sqrt_d, zs = b * inv_sqrt_d;
  const float m_ = 1.f / (1.f + __expf(-zm));
  const float sp = (zs > 20.f) ? zs : log1pf(__expf(zs));
  const float s2 = fmaxf(sp, 1e-4f);
  float ivs[2], cof[2];
  ivs[0] = rsqrtf(s2 + 2.5e-5f);  // b_sigma = 0.005 (even n)
  ivs[1] = rsqrtf(s2 + 1e-4f);    // b_sigma = 0.01  (odd n)
  cof[0] = 0.3989422804014327f * ivs[0];
  cof[1] = 0.3989422804014327f * ivs[1];
  const int cidx = SWZ((r0 >> 4) * 64 + kc * 16 + (r0 & 15));
  auto stageB = [&](int bb, int kk) {  // 4 gload16 per lane
#pragma unroll
    for (int i = 0; i < 2; i++) {
      int sub = wave + i * 4;  // B subtiles 0..7 (128 d-cols)
      int m = sub * 16 + srow;
      gload16(VTh + voff + (long long)m * kNB + kk + skc * 8, &lBh[bb][sub * 64]);
      gload16(VTl + voff + (long long)m * kNB + kk + skc * 8, &lBl[bb][sub * 64]);
    }
  };
  auto stageA = [&](int bb, int kk) {  // 2 ds_write per lane (swizzled slots)
    s16x8 hv, lv;
#pragma unroll
    for (int jj = 0; jj < 8; jj++) {
      int n = kk + kc * 8 + jj;
      float bmu = (float)(n >> 1) * (1.f / 511.f);
      int p = jj & 1;  // parity of n (kk, kc*8 even)
      float tt = (bmu - m_) * ivs[p];
      float v = cof[p] * __expf(-0.5f * tt * tt);
      short hb = f2bf(v);
      hv[jj] = hb;
      lv[jj] = f2bf(v - bf2f(hb));
    }
    lAh[bb][cidx] = hv;
    lAl[bb][cidx] = lv;
  };
  f32x4 acc[2][4];
  const f32x4 z = {0.f, 0.f, 0.f, 0.f};
#pragma unroll
  for (int i = 0; i < 2; i++)
#pragma unroll
    for (int j = 0; j < 4; j++) acc[i][j] = z;
  stageB(0, 0);
  stageA(0, 0);
  stageB(1, 32);
  stageA(1, 32);
  VMLB(4);
  const int NT = kNB >> 5;  // 32
  int cur = 0, pf = 2;
  for (int tt = 0; tt < NT; ++tt) {
    const bool more = (tt + 2 < NT);
    if (more) {
      stageB(pf, (tt + 2) << 5);   // async loads issued first
      stageA(pf, (tt + 2) << 5);   // ds_writes precede this iter's ds_reads (in-order DS)
    }
    s16x8 ah[2], al[2], bh[4], bl[4];
#pragma unroll
    for (int i = 0; i < 2; i++) {
      ah[i] = lAh[cur][SWZ((wm * 2 + i) * 64 + lane)];
      al[i] = lAl[cur][SWZ((wm * 2 + i) * 64 + lane)];
    }
#pragma unroll
    for (int j = 0; j < 4; j++) {
      bh[j] = lBh[cur][(wn * 4 + j) * 64 + lane];
      bl[j] = lBl[cur][(wn * 4 + j) * 64 + lane];
    }
#pragma unroll
    for (int i = 0; i < 2; i++)
#pragma unroll
      for (int j = 0; j < 4; j++) {
        acc[i][j] = __builtin_amdgcn_mfma_f32_16x16x32_bf16(ah[i], bh[j], acc[i][j], 0, 0, 0);
        acc[i][j] = __builtin_amdgcn_mfma_f32_16x16x32_bf16(ah[i], bl[j], acc[i][j], 0, 0, 0);
        acc[i][j] = __builtin_amdgcn_mfma_f32_16x16x32_bf16(al[i], bh[j], acc[i][j], 0, 0, 0);
      }
    if (more) VMLB(4); else VMLB(0);
    cur = (cur == 2) ? 0 : cur + 1;
    pf = (pf == 2) ? 0 : pf + 1;
  }
  short* Cp = ctx + h * kD;
#pragma unroll
  for (int i = 0; i < 2; i++)
#pragma unroll
    for (int j = 0; j < 4; j++) {
      int gn = (wn * 4 + j) * 16 + l16;
#pragma unroll
      for (int rg = 0; rg < 4; rg++) {
        int gm = m0 + (wm * 2 + i) * 16 + quad * 4 + rg;
        Cp[(long long)gm * kDM + gn] = f2bf(acc[i][j][rg]);
      }
    }
}

extern "C" void kernel_launch(void* const* d_in, const int* in_sizes, int n_in,
                              void* d_out, int out_size, void* d_ws, size_t ws_size,
                              hipStream_t stream) {
  (void)in_sizes; (void)n_in; (void)out_size; (void)ws_size;
  const void* kmem = d_in[0];
  const void* q    = d_in[1];
  const void* Wk   = d_in[2];
  const void* Wv   = d_in[3];
  const void* Wo   = d_in[4];
  const void* wmu  = d_in[5];
  const void* wsg  = d_in[6];

  // ---- workspace layout (~32.5 MB total) ----
  char* ws = (char*)d_ws;
  short* k_bf  = (short*)ws;                          // [512][2048] bf16, 2 MB
  short* kvT   = (short*)(ws + ((size_t)2 << 20));    // [2048][512] bf16, 2 MB
  short* Wv_bf = (short*)(ws + ((size_t)4 << 20));    // [2048][2048] bf16, 8 MB (dead after kv)
  short* Wo_bf = Wv_bf;                               // overlay AFTER kv GEMM
  float* Pbuf  = (float*)(ws + ((size_t)12 << 20));   // [4][512][2048] f32, 16 MB
  short* VTh   = (short*)(ws + ((size_t)12 << 20));   // [2048][1024] bf16, 4 MB (overlays Pbuf)
  short* VTl   = (short*)(ws + ((size_t)16 << 20));   // [2048][1024] bf16, 4 MB
  short* ctx   = (short*)(ws + ((size_t)20 << 20));   // [2048][2048] bf16, 8 MB
  float* tail  = (float*)(ws + ((size_t)28 << 20));
  float* gw    = tail;                 // 2*512
  float* bw    = gw + 2 * kML;         // 2*2048
  float* kw    = bw + 2 * kDM;         // 2*2048
  int*   flag  = (int*)(kw + 2 * kDM);
  float* gtffall = (float*)(ws + ((size_t)28 << 20) + ((size_t)1 << 19));  // 2 MB @28.5
  short* ghfall  = (short*)(ws + ((size_t)30 << 20) + ((size_t)1 << 19));  // 1 MB @30.5
  short* glfall  = (short*)(ws + ((size_t)31 << 20) + ((size_t)1 << 19));  // 1 MB @31.5

  const float* GtTf = g_init.d_GtTf;
  if (!GtTf) {
    const void* src = g_init.h_GtTf_pinned ? (const void*)g_init.h_GtTf_pinned
                                           : (const void*)g_init.h_GtTf.data();
    hipMemcpyAsync(gtffall, src, (size_t)kNB * kML * 4, hipMemcpyHostToDevice, stream);
    GtTf = gtffall;
  }
  const short* Gh = (const short*)g_init.d_Gth;
  if (!Gh) {
    const void* src = g_init.h_Gth_pinned ? (const void*)g_init.h_Gth_pinned
                                          : (const void*)g_init.h_Gth.data();
    hipMemcpyAsync(ghfall, src, (size_t)kNB * kML * 2, hipMemcpyHostToDevice, stream);
    Gh = ghfall;
  }
  const short* Gl = (const short*)g_init.d_Gtl;
  if (!Gl) {
    const void* src = g_init.h_Gtl_pinned ? (const void*)g_init.h_Gtl_pinned
                                          : (const void*)g_init.h_Gtl.data();
    hipMemcpyAsync(glfall, src, (size_t)kNB * kML * 2, hipMemcpyHostToDevice, stream);
    Gl = glfall;
  }

  // 1) fused dtype-detect + k/Wv -> bf16 + zero bw (flag published downstream)
  prep_kernel<<<5120, 256, 0, stream>>>((const unsigned short*)q, kmem, Wv,
                                        k_bf, Wv_bf, bw, flag);

  // 2) exact f32 mu/sigma inputs: gw -> bw (atomic, 128 blocks) -> kw
  gw_kernel<<<kML, 256, 0, stream>>>(GtTf, wmu, wsg, gw, flag);
  bwk_kernel<<<dim3(kDM / 256, kML / 32), 256, 0, stream>>>(kmem, gw, bw, flag);
  kw_kernel<<<kDM, 256, 0, stream>>>(Wk, bw, kw, flag);

  // 3) kv GEMM split-K=4: P[z][l][d] partials. 128x64 tiles -> 512 blocks (2/CU).
  mfma_gemm_sk<<<dim3(kDM / 64, kML / 128, 4), 256, 0, stream>>>(
      k_bf, kDM, Wv_bf, kDM, Pbuf, kDM);
  // reduce partials -> kvT[d][l] bf16 (single f2bf rounding)
  reduceT_kernel<<<dim3(kDM / 64, kML / 64), 256, 0, stream>>>(Pbuf, kvT);

  // 4) Wo -> bf16 (overlays Wv_bf, dead after kv GEMM)
  conv_bf16<<<(kDM * kDM / 4 + 255) / 256, 256, 0, stream>>>(Wo, Wo_bf, kDM * kDM / 4, flag);

  // 5) valuesT[d][n] = sum_l kvT[d][l] * G[l][n]  (split G in, split VT out)
  mfma_gemm_bt2<<<dim3(kNB / 64, kDM / 64, 1), 256, 0, stream>>>(
      kvT, kML, Gh, Gl, kML, VTh, VTl, kNB, kML);

  // 6) ctx = r @ valuesT (mu/sigma inlined; 3-pass split x split)
  mfma_rv<<<dim3(1, kQL / 64, kH), 256, 0, stream>>>(q, kw, flag, VTh, VTl, ctx);

  // 7) out = ctx @ Wo^T  (runtime out dtype). 128x64 tiles -> grid (32, 16) = 512.
  mfma_gemm_bt<2><<<dim3(kDM / 64, kQL / 128, 1), 256, 0, stream>>>(
      ctx, kDM, 0, Wo_bf, kDM, 0, d_out, kDM, 0, kDM, flag);
}

// Round 15
// 257.484 us; speedup vs baseline: 1.1853x; 1.0003x over previous
//
#include <hip/hip_runtime.h>
#include <hip/hip_bf16.h>
#include <vector>
#include <cmath>
#include <cstring>

using bf16 = __hip_bfloat16;
typedef short s16x8 __attribute__((ext_vector_type(8)));
typedef float f32x4 __attribute__((ext_vector_type(4)));

static constexpr int kH = 16, kD = 128, kNB = 1024, kML = 512, kQL = 2048, kDM = 2048;

// counted-vmcnt barrier (m201 pattern)
#define VMB(N) do { asm volatile("s_waitcnt vmcnt(" #N ")" ::: "memory"); \
                    __builtin_amdgcn_s_barrier(); \
                    asm volatile("" ::: "memory"); } while (0)
#define VMLB(N) do { asm volatile("s_waitcnt vmcnt(" #N ") lgkmcnt(0)" ::: "memory"); \
                     __builtin_amdgcn_s_barrier(); \
                     asm volatile("" ::: "memory"); } while (0)
// bank-conflict swizzle for VALU-staged (ds_write) LDS tiles; involution,
// applied identically on write and read. NOT used on global_load_lds tiles.
#define SWZ(c) ((c) ^ (((c) >> 4) & 3))

// ================= host precompute of Gt (input-independent) =================
static void compute_Gt_host(float* Gt) {
  const int n = kNB, P = 2 * kML;
  std::vector<double> F((size_t)n * P), A((size_t)n * n), pos(P);
  const double shift = 1.0 / (double)P;
  const double p0 = -0.5 + shift, p1 = 1.5 - shift;
  for (int i = 0; i < P; i++) pos[i] = p0 + (p1 - p0) * (double)i / (double)(P - 1);
  const double c0 = 0.3989422804014327;
  std::vector<int> lo(n), hi(n);
  for (int b = 0; b < n; b++) {
    double mu = (double)(b >> 1) / 511.0;
    double sg = (b & 1) ? 0.01 : 0.005;
    double c = c0 / sg;
    double* Fb = &F[(size_t)b * P];
    for (int i = 0; i < P; i++) { double t = (pos[i] - mu) / sg; Fb[i] = c * exp(-0.5 * t * t); }
    int l = 0; while (l < P - 1 && pos[l] < mu - 14.0 * sg) l++;
    int h = P - 1; while (h > 0 && pos[h] > mu + 14.0 * sg) h--;
    lo[b] = l; hi[b] = h;
  }
  for (int i = 0; i < n; i++) {
    const double* fi = &F[(size_t)i * P];
    for (int j = 0; j <= i; j++) {
      const double* fj = &F[(size_t)j * P];
      int a = lo[i] > lo[j] ? lo[i] : lo[j];
      int b2 = hi[i] < hi[j] ? hi[i] : hi[j];
      double s = 0.0;
      for (int k2 = a; k2 <= b2; k2++) s += fi[k2] * fj[k2];
      A[(size_t)i * n + j] = s;
      if (i != j) A[(size_t)j * n + i] = s;
    }
    A[(size_t)i * n + i] += 0.5;
  }
  for (int j = 0; j < n; j++) {  // Cholesky
    double* Aj = &A[(size_t)j * n];
    double d = Aj[j];
    for (int k2 = 0; k2 < j; k2++) d -= Aj[k2] * Aj[k2];
    d = std::sqrt(d); Aj[j] = d;
    double inv = 1.0 / d;
    for (int i = j + 1; i < n; i++) {
      double* Ai = &A[(size_t)i * n];
      double s = Ai[j];
      for (int k2 = 0; k2 < j; k2++) s -= Ai[k2] * Aj[k2];
      Ai[j] = s * inv;
    }
  }
  for (int i = 0; i < n; i++) {  // L Y = F
    double* yi = &F[(size_t)i * P];
    const double* Ai = &A[(size_t)i * n];
    for (int k2 = 0; k2 < i; k2++) {
      double lik = Ai[k2];
      const double* yk = &F[(size_t)k2 * P];
      for (int t = 0; t < P; t++) yi[t] -= lik * yk[t];
    }
    double inv = 1.0 / Ai[i];
    for (int t = 0; t < P; t++) yi[t] *= inv;
  }
  for (int i = n - 1; i >= 0; i--) {  // L^T X = Y
    double* xi = &F[(size_t)i * P];
    for (int k2 = i + 1; k2 < n; k2++) {
      double lki = A[(size_t)k2 * n + i];
      const double* xk = &F[(size_t)k2 * P];
      for (int t = 0; t < P; t++) xi[t] -= lki * xk[t];
    }
    double inv = 1.0 / A[(size_t)i * n + i];
    for (int t = 0; t < P; t++) xi[t] *= inv;
  }
  for (int b = 0; b < n; b++)
    for (int l = 0; l < kML; l++)
      Gt[(size_t)b * kML + l] = (float)F[(size_t)b * P + (kML / 2) + l];
}

static unsigned short f2bf_host(float x) {
  unsigned u; std::memcpy(&u, &x, 4);
  unsigned r = (u + 0x7FFFu + ((u >> 16) & 1u)) >> 16;
  return (unsigned short)r;
}
static float bf2f_host(unsigned short b) {
  unsigned u = ((unsigned)b) << 16; float f; std::memcpy(&f, &u, 4); return f;
}

namespace {
struct Init {
  float* d_GtTf = nullptr;           // f32 GtT[l][n]  [512][1024]
  unsigned short* d_Gth = nullptr;   // bf16-hi Gt[n][l]  [1024][512]
  unsigned short* d_Gtl = nullptr;   // bf16-lo Gt[n][l]  [1024][512]
  float* h_GtTf_pinned = nullptr;
  unsigned short* h_Gth_pinned = nullptr;
  unsigned short* h_Gtl_pinned = nullptr;
  std::vector<float> h_GtTf;
  std::vector<unsigned short> h_Gth, h_Gtl;
  Init() {
    std::vector<float> h_Gt((size_t)kNB * kML);
    compute_Gt_host(h_Gt.data());
    h_GtTf.resize(h_Gt.size());
    h_Gth.resize(h_Gt.size());
    h_Gtl.resize(h_Gt.size());
    for (int n = 0; n < kNB; n++)
      for (int l = 0; l < kML; l++) {
        float v = h_Gt[(size_t)n * kML + l];
        h_GtTf[(size_t)l * kNB + n] = v;
        unsigned short hb = f2bf_host(v);
        h_Gth[(size_t)n * kML + l] = hb;
        h_Gtl[(size_t)n * kML + l] = f2bf_host(v - bf2f_host(hb));
      }
    const size_t fb = h_Gt.size() * 4, bb = h_Gt.size() * 2;
    if (hipMalloc((void**)&d_GtTf, fb) == hipSuccess) {
      if (hipMemcpy(d_GtTf, h_GtTf.data(), fb, hipMemcpyHostToDevice) != hipSuccess) { hipFree(d_GtTf); d_GtTf = nullptr; }
    }
    if (hipMalloc((void**)&d_Gth, bb) == hipSuccess) {
      if (hipMemcpy(d_Gth, h_Gth.data(), bb, hipMemcpyHostToDevice) != hipSuccess) { hipFree(d_Gth); d_Gth = nullptr; }
    }
    if (hipMalloc((void**)&d_Gtl, bb) == hipSuccess) {
      if (hipMemcpy(d_Gtl, h_Gtl.data(), bb, hipMemcpyHostToDevice) != hipSuccess) { hipFree(d_Gtl); d_Gtl = nullptr; }
    }
    if (!d_GtTf && hipHostMalloc((void**)&h_GtTf_pinned, fb, 0) == hipSuccess)
      std::memcpy(h_GtTf_pinned, h_GtTf.data(), fb);
    if (!d_Gth && hipHostMalloc((void**)&h_Gth_pinned, bb, 0) == hipSuccess)
      std::memcpy(h_Gth_pinned, h_Gth.data(), bb);
    if (!d_Gtl && hipHostMalloc((void**)&h_Gtl_pinned, bb, 0) == hipSuccess)
      std::memcpy(h_Gtl_pinned, h_Gtl.data(), bb);
  }
};
Init g_init;
}

// ================= device helpers =================
__device__ inline short f2bf(float x) {
  unsigned u = __float_as_uint(x);
  unsigned r = (u + 0x7FFFu + ((u >> 16) & 1u)) >> 16;
  return (short)r;
}
__device__ inline float bf2f(short b) {
  return __uint_as_float(((unsigned)(unsigned short)b) << 16);
}

// async global->LDS, 16 B per lane; LDS dest is wave-uniform base + lane*16.
__device__ inline void gload16(const void* g, void* l) {
  __builtin_amdgcn_global_load_lds(
      (__attribute__((address_space(1))) void*)(g),
      (__attribute__((address_space(3))) void*)(l),
      16, 0, 0);
}

// local dtype detection: read first 512 ushorts of q; exponent-field >= 0x98
// occurs (w.h.p.) iff data is f32 (mantissa low-halves are ~uniform).
__device__ inline int detect_local(const unsigned short* q) {
  int bad = 0;
  for (int i = threadIdx.x; i < 512; i += 256) {
    int e = (q[i] >> 7) & 0xFF;
    if (e >= 0x98) bad = 1;
  }
  __shared__ int s[256];
  s[threadIdx.x] = bad; __syncthreads();
  for (int k2 = 128; k2 > 0; k2 >>= 1) {
    if (threadIdx.x < k2) s[threadIdx.x] |= s[threadIdx.x + k2];
    __syncthreads();
  }
  return s[0];
}

// ===== fused prep: dtype detect + convert k/Wv to bf16 + zero bw + flag =======
// grid: [0,1024) -> k (512x2048), [1024,5120) -> Wv (2048x2048). 4 elems/thread.
// Block 0 additionally zeroes bw (4096 f32) for the downstream atomic bwk.
__global__ __launch_bounds__(256) void prep_kernel(const unsigned short* __restrict__ q,
                                                   const void* __restrict__ kin,
                                                   const void* __restrict__ Wv,
                                                   short* __restrict__ k_bf,
                                                   short* __restrict__ Wv_bf,
                                                   float* __restrict__ bw,
                                                   int* __restrict__ flag) {
  const int f32 = detect_local(q);
  if (blockIdx.x == 0) {
    if (threadIdx.x == 0) *flag = f32;
    for (int i = threadIdx.x; i < 2 * kDM; i += 256) bw[i] = 0.f;
  }
  const void* src; short* dst; int i;
  if (blockIdx.x < 1024) { src = kin; dst = k_bf; i = blockIdx.x * 256 + threadIdx.x; }
  else { src = Wv; dst = Wv_bf; i = (blockIdx.x - 1024) * 256 + threadIdx.x; }
  if (f32) {
    float4 v = ((const float4*)src)[i];
    short4 o; o.x = f2bf(v.x); o.y = f2bf(v.y); o.z = f2bf(v.z); o.w = f2bf(v.w);
    ((short4*)dst)[i] = o;
  } else {
    ((short4*)dst)[i] = ((const short4*)src)[i];
  }
}

// elementwise convert (f32|bf16 in) -> bf16, 4 elems/thread (used for Wo)
__global__ __launch_bounds__(256) void conv_bf16(const void* __restrict__ in,
                                                 short* __restrict__ out, int n4,
                                                 const int* __restrict__ flag) {
  int i = blockIdx.x * 256 + threadIdx.x;
  if (i >= n4) return;
  if (*flag) {
    float4 v = ((const float4*)in)[i];
    short4 o; o.x = f2bf(v.x); o.y = f2bf(v.y); o.z = f2bf(v.z); o.w = f2bf(v.w);
    ((short4*)out)[i] = o;
  } else {
    ((short4*)out)[i] = ((const short4*)in)[i];
  }
}

// ===== exact f32 mu/sigma path =====
__global__ __launch_bounds__(256) void gw_kernel(const float* __restrict__ GtT,
                                                 const void* __restrict__ wmu,
                                                 const void* __restrict__ wsg,
                                                 float* __restrict__ gw,
                                                 const int* __restrict__ flag) {
  const bool f32 = (*flag != 0);
  const int l = blockIdx.x, t = threadIdx.x;
  const float* row = GtT + (long long)l * kNB;
  float a = 0.f, b = 0.f;
  for (int n = t; n < kNB; n += 256) {
    float g = row[n];
    float wm_ = f32 ? ((const float*)wmu)[n] : bf2f(((const short*)wmu)[n]);
    float ws_ = f32 ? ((const float*)wsg)[n] : bf2f(((const short*)wsg)[n]);
    a += g * wm_; b += g * ws_;
  }
  __shared__ float red[2][256];
  red[0][t] = a; red[1][t] = b;
  __syncthreads();
  for (int s = 128; s > 0; s >>= 1) {
    if (t < s) { red[0][t] += red[0][t + s]; red[1][t] += red[1][t + s]; }
    __syncthreads();
  }
  if (t == 0) { gw[l] = red[0][0]; gw[kML + l] = red[1][0]; }
}

// bw[j] += sum_{l in chunk} k[l][j] * gw[l]  -- grid (8 j-blocks, 16 l-chunks),
// coalesced row reads, atomic combine (bw pre-zeroed by prep_kernel).
__global__ __launch_bounds__(256) void bwk_kernel(const void* __restrict__ kin,
                                                  const float* __restrict__ gw,
                                                  float* __restrict__ bw,
                                                  const int* __restrict__ flag) {
  const bool f32 = (*flag != 0);
  int j = blockIdx.x * 256 + threadIdx.x;
  int l0 = blockIdx.y * 32;
  float a = 0.f, b = 0.f;
  for (int l = l0; l < l0 + 32; l++) {
    float kv = f32 ? ((const float*)kin)[(long long)l * kDM + j]
                   : bf2f(((const short*)kin)[(long long)l * kDM + j]);
    a += kv * gw[l]; b += kv * gw[kML + l];
  }
  atomicAdd(&bw[j], a);
  atomicAdd(&bw[kDM + j], b);
}

__global__ __launch_bounds__(256) void kw_kernel(const void* __restrict__ Wk,
                                                 const float* __restrict__ bw,
                                                 float* __restrict__ kw,
                                                 const int* __restrict__ flag) {
  const bool f32 = (*flag != 0);
  int i = blockIdx.x;
  float smu = 0.f, ssg = 0.f;
  if (f32) {
    const float* row = (const float*)Wk + (long long)i * kDM;
    for (int j = threadIdx.x; j < kDM; j += 256) { float w = row[j]; smu += w * bw[j]; ssg += w * bw[kDM + j]; }
  } else {
    const short* row = (const short*)Wk + (long long)i * kDM;
    for (int j = threadIdx.x; j < kDM; j += 256) { float w = bf2f(row[j]); smu += w * bw[j]; ssg += w * bw[kDM + j]; }
  }
  __shared__ float red[2][256];
  red[0][threadIdx.x] = smu; red[1][threadIdx.x] = ssg;
  __syncthreads();
  for (int s = 128; s > 0; s >>= 1) {
    if (threadIdx.x < (unsigned)s) {
      red[0][threadIdx.x] += red[0][threadIdx.x + s];
      red[1][threadIdx.x] += red[1][threadIdx.x + s];
    }
    __syncthreads();
  }
  if (threadIdx.x == 0) { kw[i] = red[0][0]; kw[kDM + i] = red[1][0]; }
}

// ===== MFMA GEMM: C[M,N] = A[M,K] @ BT[N,K]^T (bf16 in, f32 acc) ===============
// Tile 128x64, BK=64. 3-buffer pipeline, prefetch distance 2, counted vmcnt(6).
// LDS 72 KB -> 2 blocks/CU (grid 512). XCD-rectangle swizzle (when grid 32x16):
// each XCD (bid%8) gets an 8n x 8m rectangle -> per-XCD L2 working set = 2 MB Wo
// + 4 MB ctx (vs 9 MB unswizzled thrash). Bijective. CSTORE: 0 bf16; 2 runtime.
template <int CSTORE>
__global__ __launch_bounds__(256) void mfma_gemm_bt(
    const short* __restrict__ A0, int lda, long long sA,
    const short* __restrict__ BT0, int ldb, long long sB,
    void* __restrict__ C0, int ldc, long long sC,
    int K, const int* __restrict__ flag) {
  __shared__ s16x8 lA[3][1024];  // [buf][ks*512 + sub*64 + lane]
  __shared__ s16x8 lB[3][512];   // [buf][ks*256 + sub*64 + lane]
  const short* A = A0 + (long long)blockIdx.z * sA;
  const short* BT = BT0 + (long long)blockIdx.z * sB;
  const int t = threadIdx.x;
  const int wave = t >> 6, lane = t & 63;
  const int quad = lane >> 4, l16 = lane & 15;
  const int wm = wave >> 1, wn = wave & 1;
  int m0, n0;
  if (gridDim.x == 32 && gridDim.y == 16) {
    const int bid = blockIdx.x + (blockIdx.y << 5);
    const int xcd = bid & 7, rank = bid >> 3;
    n0 = (((xcd & 3) << 3) + (rank & 7)) * 64;
    m0 = (((xcd >> 2) << 3) + (rank >> 3)) * 128;
  } else {
    m0 = blockIdx.y * 128; n0 = blockIdx.x * 64;
  }
  const int srow = lane & 15, skc = lane >> 4;
  auto stage = [&](int b, int kk) {              // 6 gload16 per lane
#pragma unroll
    for (int i = 0; i < 2; i++) {
      int sub = wave + i * 4;         // A subtiles 0..7
      int m = sub * 16 + srow;
#pragma unroll
      for (int ks = 0; ks < 2; ks++)
        gload16(A + (long long)(m0 + m) * lda + kk + ks * 32 + skc * 8,
                &lA[b][ks * 512 + sub * 64]);
    }
    int mB = wave * 16 + srow;        // B subtiles 0..3, one per wave
#pragma unroll
    for (int ks = 0; ks < 2; ks++)
      gload16(BT + (long long)(n0 + mB) * ldb + kk + ks * 32 + skc * 8,
              &lB[b][ks * 256 + wave * 64]);
  };
  f32x4 acc[4][2];
  const f32x4 z = {0.f, 0.f, 0.f, 0.f};
#pragma unroll
  for (int i = 0; i < 4; i++)
#pragma unroll
    for (int j = 0; j < 2; j++) acc[i][j] = z;
  stage(0, 0);
  stage(1, 64);
  VMB(6);                       // tile 0 landed; tile 1 in flight
  const int NT = K >> 6;
  int cur = 0, pf = 2;
  for (int tt = 0; tt < NT; ++tt) {
    const bool more = (tt + 2 < NT);
    if (more) stage(pf, (tt + 2) << 6);
#pragma unroll
    for (int ks = 0; ks < 2; ks++) {
      s16x8 af[4], bfr[2];
#pragma unroll
      for (int i = 0; i < 4; i++) af[i] = lA[cur][ks * 512 + (wm * 4 + i) * 64 + lane];
#pragma unroll
      for (int j = 0; j < 2; j++) bfr[j] = lB[cur][ks * 256 + (wn * 2 + j) * 64 + lane];
#pragma unroll
      for (int i = 0; i < 4; i++)
#pragma unroll
        for (int j = 0; j < 2; j++)
          acc[i][j] = __builtin_amdgcn_mfma_f32_16x16x32_bf16(af[i], bfr[j], acc[i][j], 0, 0, 0);
    }
    if (more) VMB(6); else VMB(0);
    cur = (cur == 2) ? 0 : cur + 1;
    pf = (pf == 2) ? 0 : pf + 1;
  }
  // epilogue: C/D layout col=lane&15, row=quad*4+reg
  if (CSTORE == 0) {
    short* Cp = (short*)C0 + (long long)blockIdx.z * sC;
#pragma unroll
    for (int i = 0; i < 4; i++)
#pragma unroll
      for (int j = 0; j < 2; j++) {
        int gn = n0 + (wn * 2 + j) * 16 + l16;
#pragma unroll
        for (int rg = 0; rg < 4; rg++) {
          int gm = m0 + (wm * 4 + i) * 16 + quad * 4 + rg;
          Cp[(long long)gm * ldc + gn] = f2bf(acc[i][j][rg]);
        }
      }
  } else {
    if (*flag) {
      float* Cp = (float*)C0 + (long long)blockIdx.z * sC;
#pragma unroll
      for (int i = 0; i < 4; i++)
#pragma unroll
        for (int j = 0; j < 2; j++) {
          int gn = n0 + (wn * 2 + j) * 16 + l16;
#pragma unroll
          for (int rg = 0; rg < 4; rg++) {
            int gm = m0 + (wm * 4 + i) * 16 + quad * 4 + rg;
            Cp[(long long)gm * ldc + gn] = acc[i][j][rg];
          }
        }
    } else {
      short* Cp = (short*)C0 + (long long)blockIdx.z * sC;
#pragma unroll
      for (int i = 0; i < 4; i++)
#pragma unroll
        for (int j = 0; j < 2; j++) {
          int gn = n0 + (wn * 2 + j) * 16 + l16;
#pragma unroll
          for (int rg = 0; rg < 4; rg++) {
            int gm = m0 + (wm * 4 + i) * 16 + quad * 4 + rg;
            Cp[(long long)gm * ldc + gn] = f2bf(acc[i][j][rg]);
          }
        }
    }
  }
}

// ===== split-K kv GEMM: P[z][l][d] = k[l][:] @ Wv[d][:] over K-chunk z ========
// Tile 128x64, BK=64, 3-buffer counted-vmcnt pipeline (as bt). Grid 512 blocks.
__global__ __launch_bounds__(256) void mfma_gemm_sk(
    const short* __restrict__ A0, int lda,      // k_bf [512][2048]
    const short* __restrict__ BT0, int ldb,     // Wv_bf [2048][2048]
    float* __restrict__ P, int ldc) {           // [4][512][2048] f32
  __shared__ s16x8 lA[3][1024], lB[3][512];  // 72 KB
  const int t = threadIdx.x;
  const int wave = t >> 6, lane = t & 63;
  const int quad = lane >> 4, l16 = lane & 15;
  const int wm = wave >> 1, wn = wave & 1;
  const int m0 = blockIdx.y * 128, n0 = blockIdx.x * 64;
  const int kbeg = blockIdx.z * 512;
  const int srow = lane & 15, skc = lane >> 4;
  auto stage = [&](int b, int kk) {  // 6 gload16 per lane
#pragma unroll
    for (int i = 0; i < 2; i++) {
      int sub = wave + i * 4;
      int m = sub * 16 + srow;
#pragma unroll
      for (int ks = 0; ks < 2; ks++)
        gload16(A0 + (long long)(m0 + m) * lda + kk + ks * 32 + skc * 8,
                &lA[b][ks * 512 + sub * 64]);
    }
    int mB = wave * 16 + srow;
#pragma unroll
    for (int ks = 0; ks < 2; ks++)
      gload16(BT0 + (long long)(n0 + mB) * ldb + kk + ks * 32 + skc * 8,
              &lB[b][ks * 256 + wave * 64]);
  };
  f32x4 acc[4][2];
  const f32x4 z = {0.f, 0.f, 0.f, 0.f};
#pragma unroll
  for (int i = 0; i < 4; i++)
#pragma unroll
    for (int j = 0; j < 2; j++) acc[i][j] = z;
  stage(0, kbeg);
  stage(1, kbeg + 64);
  VMB(6);
  const int NT = 8;  // 512/64
  int cur = 0, pf = 2;
  for (int tt = 0; tt < NT; ++tt) {
    const bool more = (tt + 2 < NT);
    if (more) stage(pf, kbeg + ((tt + 2) << 6));
#pragma unroll
    for (int ks = 0; ks < 2; ks++) {
      s16x8 af[4], bfr[2];
#pragma unroll
      for (int i = 0; i < 4; i++) af[i] = lA[cur][ks * 512 + (wm * 4 + i) * 64 + lane];
#pragma unroll
      for (int j = 0; j < 2; j++) bfr[j] = lB[cur][ks * 256 + (wn * 2 + j) * 64 + lane];
#pragma unroll
      for (int i = 0; i < 4; i++)
#pragma unroll
        for (int j = 0; j < 2; j++)
          acc[i][j] = __builtin_amdgcn_mfma_f32_16x16x32_bf16(af[i], bfr[j], acc[i][j], 0, 0, 0);
    }
    if (more) VMB(6); else VMB(0);
    cur = (cur == 2) ? 0 : cur + 1;
    pf = (pf == 2) ? 0 : pf + 1;
  }
  float* Cp = P + (long long)blockIdx.z * kML * kDM;
#pragma unroll
  for (int i = 0; i < 4; i++)
#pragma unroll
    for (int j = 0; j < 2; j++) {
      int gn = n0 + (wn * 2 + j) * 16 + l16;
#pragma unroll
      for (int rg = 0; rg < 4; rg++) {
        int gm = m0 + (wm * 4 + i) * 16 + quad * 4 + rg;
        Cp[(long long)gm * ldc + gn] = acc[i][j][rg];
      }
    }
}

// reduce 4 f32 partials [z][l][d] -> kvT bf16 [d][l] (LDS transpose)
__global__ __launch_bounds__(256) void reduceT_kernel(const float* __restrict__ P,
                                                      short* __restrict__ kvT) {
  __shared__ float tile[64][65];
  const int bd = blockIdx.x, bl = blockIdx.y;  // 32 x 8
  const int tx = threadIdx.x & 63, ty = threadIdx.x >> 6;
  for (int i = ty; i < 64; i += 4) {
    int l = bl * 64 + i, d = bd * 64 + tx;
    float s = 0.f;
#pragma unroll
    for (int z = 0; z < 4; z++) s += P[((long long)z * kML + l) * kDM + d];
    tile[i][tx] = s;
  }
  __syncthreads();
  for (int i = ty; i < 64; i += 4) {
    int d = bd * 64 + i, l = bl * 64 + tx;
    kvT[(long long)d * kML + l] = f2bf(tile[tx][i]);
  }
}

// ===== split-B GEMM with SPLIT OUTPUT ==========================================
// Tile 64x64, BK=32, 3-buffer counted-vmcnt(3) pipeline. Grid 512. LDS 36 KB.
__global__ __launch_bounds__(256) void mfma_gemm_bt2(
    const short* __restrict__ A0, int lda,
    const short* __restrict__ BTh, const short* __restrict__ BTl, int ldb,
    short* __restrict__ Ch, short* __restrict__ Cl, int ldc, int K) {
  __shared__ s16x8 lA[3][256], lBh[3][256], lBl[3][256];  // 36 KB
  const int t = threadIdx.x;
  const int wave = t >> 6, lane = t & 63;
  const int quad = lane >> 4, l16 = lane & 15;
  const int wm = wave >> 1, wn = wave & 1;
  const int m0 = blockIdx.y * 64, n0 = blockIdx.x * 64;
  const int srow = lane & 15, skc = lane >> 4;
  auto stage = [&](int b, int kk) {  // 3 gload16 per lane
    int m = wave * 16 + srow;
    gload16(A0 + (long long)(m0 + m) * lda + kk + skc * 8, &lA[b][wave * 64]);
    gload16(BTh + (long long)(n0 + m) * ldb + kk + skc * 8, &lBh[b][wave * 64]);
    gload16(BTl + (long long)(n0 + m) * ldb + kk + skc * 8, &lBl[b][wave * 64]);
  };
  f32x4 acc[2][2];
  const f32x4 z = {0.f, 0.f, 0.f, 0.f};
#pragma unroll
  for (int i = 0; i < 2; i++)
#pragma unroll
    for (int j = 0; j < 2; j++) acc[i][j] = z;
  stage(0, 0);
  stage(1, 32);
  VMB(3);
  const int NT = K >> 5;
  int cur = 0, pf = 2;
  for (int tt = 0; tt < NT; ++tt) {
    const bool more = (tt + 2 < NT);
    if (more) stage(pf, (tt + 2) << 5);
    s16x8 af[2], bh[2], bl[2];
#pragma unroll
    for (int i = 0; i < 2; i++) af[i] = lA[cur][(wm * 2 + i) * 64 + lane];
#pragma unroll
    for (int j = 0; j < 2; j++) {
      bh[j] = lBh[cur][(wn * 2 + j) * 64 + lane];
      bl[j] = lBl[cur][(wn * 2 + j) * 64 + lane];
    }
#pragma unroll
    for (int i = 0; i < 2; i++)
#pragma unroll
      for (int j = 0; j < 2; j++) {
        acc[i][j] = __builtin_amdgcn_mfma_f32_16x16x32_bf16(af[i], bh[j], acc[i][j], 0, 0, 0);
        acc[i][j] = __builtin_amdgcn_mfma_f32_16x16x32_bf16(af[i], bl[j], acc[i][j], 0, 0, 0);
      }
    if (more) VMB(3); else VMB(0);
    cur = (cur == 2) ? 0 : cur + 1;
    pf = (pf == 2) ? 0 : pf + 1;
  }
#pragma unroll
  for (int i = 0; i < 2; i++)
#pragma unroll
    for (int j = 0; j < 2; j++) {
      int gn = n0 + (wn * 2 + j) * 16 + l16;
#pragma unroll
      for (int rg = 0; rg < 4; rg++) {
        int gm = m0 + (wm * 2 + i) * 16 + quad * 4 + rg;
        float v = acc[i][j][rg];
        short hb = f2bf(v);
        Ch[(long long)gm * ldc + gn] = hb;
        Cl[(long long)gm * ldc + gn] = f2bf(v - bf2f(hb));
      }
    }
}

// ===== fused r-GEMM: ctx[q][h*128+d'] = sum_n r(h,q,n) * valuesT[h*128+d'][n] ===
// Tile 64 q-rows x 128 d-cols, BK=32, 3-buffer pipeline (vmcnt(4)+lgkmcnt(0)).
// Grid (1, 512, 1) with HEAD-MAJOR decode: h = bid&15, qtile = bid>>4, so XCD
// (bid%8) hosts only heads {x, x+8} -> 1 MB VT working set fits its 4 MB L2
// (was: all 16 heads = 8 MB -> thrash, FETCH 41 MB). mu/sigma inlined; r split
// rh+rl via SWZ ds_write; VT via global_load_lds. 3 MFMA passes. LDS 72 KB.
__global__ __launch_bounds__(256) void mfma_rv(
    const void* __restrict__ q, const float* __restrict__ kw,
    const int* __restrict__ flag,
    const short* __restrict__ VTh, const short* __restrict__ VTl,  // [2048][1024]
    short* __restrict__ ctx) {                                     // [2048][2048]
  __shared__ s16x8 lAh[3][256], lAl[3][256], lBh[3][512], lBl[3][512];  // 72 KB
  const int t = threadIdx.x;
  const int wave = t >> 6, lane = t & 63;
  const int quad = lane >> 4, l16 = lane & 15;
  const int wm = wave >> 1, wn = wave & 1;
  const int bid = blockIdx.y;
  const int h = bid & 15;          // head-major: consecutive bids cycle heads
  const int m0 = (bid >> 4) * 64;  // q-rows within head
  const int r0 = t >> 2, kc = t & 3;  // r0 in [0,64): one row per 4-lane quad
  const int srow = lane & 15, skc = lane >> 4;
  const long long voff = (long long)h * kD * kNB;
  const int row = h * kQL + m0 + r0;
  // ---- inlined musig: mu, sigma^2 for this row ----
  float a = 0.f, b = 0.f;
  {
    const bool f32q = (*flag != 0);
    const float* kmu = kw + h * kD;
    const float* ksg = kw + kDM + h * kD;
    if (f32q) {
      const float* qrow = (const float*)q + (long long)row * kD;
      for (int jj = kc * 32; jj < kc * 32 + 32; jj++) {
        float qv = qrow[jj];
        a += qv * kmu[jj]; b += qv * ksg[jj];
      }
    } else {
      const short* qrow = (const short*)q + (long long)row * kD;
      for (int jj = kc * 32; jj < kc * 32 + 32; jj++) {
        float qv = bf2f(qrow[jj]);
        a += qv * kmu[jj]; b += qv * ksg[jj];
      }
    }
    a += __shfl_xor(a, 1); a += __shfl_xor(a, 2);
    b += __shfl_xor(b, 1); b += __shfl_xor(b, 2);
  }
  const float inv_sqrt_d = 0.08838834764831845f;
  const float zm = a * inv_sqrt_d, zs = b * inv_sqrt_d;
  const float m_ = 1.f / (1.f + __expf(-zm));
  const float sp = (zs > 20.f) ? zs : log1pf(__expf(zs));
  const float s2 = fmaxf(sp, 1e-4f);
  float ivs[2], cof[2];
  ivs[0] = rsqrtf(s2 + 2.5e-5f);  // b_sigma = 0.005 (even n)
  ivs[1] = rsqrtf(s2 + 1e-4f);    // b_sigma = 0.01  (odd n)
  cof[0] = 0.3989422804014327f * ivs[0];
  cof[1] = 0.3989422804014327f * ivs[1];
  const int cidx = SWZ((r0 >> 4) * 64 + kc * 16 + (r0 & 15));
  auto stageB = [&](int bb, int kk) {  // 4 gload16 per lane
#pragma unroll
    for (int i = 0; i < 2; i++) {
      int sub = wave + i * 4;  // B subtiles 0..7 (128 d-cols)
      int m = sub * 16 + srow;
      gload16(VTh + voff + (long long)m * kNB + kk + skc * 8, &lBh[bb][sub * 64]);
      gload16(VTl + voff + (long long)m * kNB + kk + skc * 8, &lBl[bb][sub * 64]);
    }
  };
  auto stageA = [&](int bb, int kk) {  // 2 ds_write per lane (swizzled slots)
    s16x8 hv, lv;
#pragma unroll
    for (int jj = 0; jj < 8; jj++) {
      int n = kk + kc * 8 + jj;
      float bmu = (float)(n >> 1) * (1.f / 511.f);
      int p = jj & 1;  // parity of n (kk, kc*8 even)
      float tt = (bmu - m_) * ivs[p];
      float v = cof[p] * __expf(-0.5f * tt * tt);
      short hb = f2bf(v);
      hv[jj] = hb;
      lv[jj] = f2bf(v - bf2f(hb));
    }
    lAh[bb][cidx] = hv;
    lAl[bb][cidx] = lv;
  };
  f32x4 acc[2][4];
  const f32x4 z = {0.f, 0.f, 0.f, 0.f};
#pragma unroll
  for (int i = 0; i < 2; i++)
#pragma unroll
    for (int j = 0; j < 4; j++) acc[i][j] = z;
  stageB(0, 0);
  stageA(0, 0);
  stageB(1, 32);
  stageA(1, 32);
  VMLB(4);
  const int NT = kNB >> 5;  // 32
  int cur = 0, pf = 2;
  for (int tt = 0; tt < NT; ++tt) {
    const bool more = (tt + 2 < NT);
    if (more) {
      stageB(pf, (tt + 2) << 5);   // async loads issued first
      stageA(pf, (tt + 2) << 5);   // ds_writes precede this iter's ds_reads (in-order DS)
    }
    s16x8 ah[2], al[2], bh[4], bl[4];
#pragma unroll
    for (int i = 0; i < 2; i++) {
      ah[i] = lAh[cur][SWZ((wm * 2 + i) * 64 + lane)];
      al[i] = lAl[cur][SWZ((wm * 2 + i) * 64 + lane)];
    }
#pragma unroll
    for (int j = 0; j < 4; j++) {
      bh[j] = lBh[cur][(wn * 4 + j) * 64 + lane];
      bl[j] = lBl[cur][(wn * 4 + j) * 64 + lane];
    }
#pragma unroll
    for (int i = 0; i < 2; i++)
#pragma unroll
      for (int j = 0; j < 4; j++) {
        acc[i][j] = __builtin_amdgcn_mfma_f32_16x16x32_bf16(ah[i], bh[j], acc[i][j], 0, 0, 0);
        acc[i][j] = __builtin_amdgcn_mfma_f32_16x16x32_bf16(ah[i], bl[j], acc[i][j], 0, 0, 0);
        acc[i][j] = __builtin_amdgcn_mfma_f32_16x16x32_bf16(al[i], bh[j], acc[i][j], 0, 0, 0);
      }
    if (more) VMLB(4); else VMLB(0);
    cur = (cur == 2) ? 0 : cur + 1;
    pf = (pf == 2) ? 0 : pf + 1;
  }
  short* Cp = ctx + h * kD;
#pragma unroll
  for (int i = 0; i < 2; i++)
#pragma unroll
    for (int j = 0; j < 4; j++) {
      int gn = (wn * 4 + j) * 16 + l16;
#pragma unroll
      for (int rg = 0; rg < 4; rg++) {
        int gm = m0 + (wm * 2 + i) * 16 + quad * 4 + rg;
        Cp[(long long)gm * kDM + gn] = f2bf(acc[i][j][rg]);
      }
    }
}

extern "C" void kernel_launch(void* const* d_in, const int* in_sizes, int n_in,
                              void* d_out, int out_size, void* d_ws, size_t ws_size,
                              hipStream_t stream) {
  (void)in_sizes; (void)n_in; (void)out_size; (void)ws_size;
  const void* kmem = d_in[0];
  const void* q    = d_in[1];
  const void* Wk   = d_in[2];
  const void* Wv   = d_in[3];
  const void* Wo   = d_in[4];
  const void* wmu  = d_in[5];
  const void* wsg  = d_in[6];

  // ---- workspace layout (~32.5 MB total) ----
  char* ws = (char*)d_ws;
  short* k_bf  = (short*)ws;                          // [512][2048] bf16, 2 MB
  short* kvT   = (short*)(ws + ((size_t)2 << 20));    // [2048][512] bf16, 2 MB
  short* Wv_bf = (short*)(ws + ((size_t)4 << 20));    // [2048][2048] bf16, 8 MB (dead after kv)
  short* Wo_bf = Wv_bf;                               // overlay AFTER kv GEMM
  float* Pbuf  = (float*)(ws + ((size_t)12 << 20));   // [4][512][2048] f32, 16 MB
  short* VTh   = (short*)(ws + ((size_t)12 << 20));   // [2048][1024] bf16, 4 MB (overlays Pbuf)
  short* VTl   = (short*)(ws + ((size_t)16 << 20));   // [2048][1024] bf16, 4 MB
  short* ctx   = (short*)(ws + ((size_t)20 << 20));   // [2048][2048] bf16, 8 MB
  float* tail  = (float*)(ws + ((size_t)28 << 20));
  float* gw    = tail;                 // 2*512
  float* bw    = gw + 2 * kML;         // 2*2048
  float* kw    = bw + 2 * kDM;         // 2*2048
  int*   flag  = (int*)(kw + 2 * kDM);
  float* gtffall = (float*)(ws + ((size_t)28 << 20) + ((size_t)1 << 19));  // 2 MB @28.5
  short* ghfall  = (short*)(ws + ((size_t)30 << 20) + ((size_t)1 << 19));  // 1 MB @30.5
  short* glfall  = (short*)(ws + ((size_t)31 << 20) + ((size_t)1 << 19));  // 1 MB @31.5

  const float* GtTf = g_init.d_GtTf;
  if (!GtTf) {
    const void* src = g_init.h_GtTf_pinned ? (const void*)g_init.h_GtTf_pinned
                                           : (const void*)g_init.h_GtTf.data();
    hipMemcpyAsync(gtffall, src, (size_t)kNB * kML * 4, hipMemcpyHostToDevice, stream);
    GtTf = gtffall;
  }
  const short* Gh = (const short*)g_init.d_Gth;
  if (!Gh) {
    const void* src = g_init.h_Gth_pinned ? (const void*)g_init.h_Gth_pinned
                                          : (const void*)g_init.h_Gth.data();
    hipMemcpyAsync(ghfall, src, (size_t)kNB * kML * 2, hipMemcpyHostToDevice, stream);
    Gh = ghfall;
  }
  const short* Gl = (const short*)g_init.d_Gtl;
  if (!Gl) {
    const void* src = g_init.h_Gtl_pinned ? (const void*)g_init.h_Gtl_pinned
                                          : (const void*)g_init.h_Gtl.data();
    hipMemcpyAsync(glfall, src, (size_t)kNB * kML * 2, hipMemcpyHostToDevice, stream);
    Gl = glfall;
  }

  // 1) fused dtype-detect + k/Wv -> bf16 + zero bw (flag published downstream)
  prep_kernel<<<5120, 256, 0, stream>>>((const unsigned short*)q, kmem, Wv,
                                        k_bf, Wv_bf, bw, flag);

  // 2) exact f32 mu/sigma inputs: gw -> bw (atomic, 128 blocks) -> kw
  gw_kernel<<<kML, 256, 0, stream>>>(GtTf, wmu, wsg, gw, flag);
  bwk_kernel<<<dim3(kDM / 256, kML / 32), 256, 0, stream>>>(kmem, gw, bw, flag);
  kw_kernel<<<kDM, 256, 0, stream>>>(Wk, bw, kw, flag);

  // 3) kv GEMM split-K=4: P[z][l][d] partials. 128x64 tiles -> 512 blocks (2/CU).
  mfma_gemm_sk<<<dim3(kDM / 64, kML / 128, 4), 256, 0, stream>>>(
      k_bf, kDM, Wv_bf, kDM, Pbuf, kDM);
  // reduce partials -> kvT[d][l] bf16 (single f2bf rounding)
  reduceT_kernel<<<dim3(kDM / 64, kML / 64), 256, 0, stream>>>(Pbuf, kvT);

  // 4) Wo -> bf16 (overlays Wv_bf, dead after kv GEMM)
  conv_bf16<<<(kDM * kDM / 4 + 255) / 256, 256, 0, stream>>>(Wo, Wo_bf, kDM * kDM / 4, flag);

  // 5) valuesT[d][n] = sum_l kvT[d][l] * G[l][n]  (split G in, split VT out)
  mfma_gemm_bt2<<<dim3(kNB / 64, kDM / 64, 1), 256, 0, stream>>>(
      kvT, kML, Gh, Gl, kML, VTh, VTl, kNB, kML);

  // 6) ctx = r @ valuesT (mu/sigma inlined; head-major XCD grouping for VT L2)
  mfma_rv<<<dim3(1, (kQL / 64) * kH, 1), 256, 0, stream>>>(q, kw, flag, VTh, VTl, ctx);

  // 7) out = ctx @ Wo^T  (runtime out dtype; XCD rectangle swizzle). Grid (32,16).
  mfma_gemm_bt<2><<<dim3(kDM / 64, kQL / 128, 1), 256, 0, stream>>>(
      ctx, kDM, 0, Wo_bf, kDM, 0, d_out, kDM, 0, kDM, flag);
}